// Round 11
// baseline (219.237 us; speedup 1.0000x reference)
//
#include <hip/hip_runtime.h>

#define C_DIM 256
#define NCODE 1024
#define MARGIN1 0.35f   // stage-1 screen (1-pass err-diff sigma ~0.07 -> 5 sigma)
#define MARGIN2 0.02f   // stage-2 screen (3-pass, validated R5+)

typedef __bf16 bf16x8 __attribute__((ext_vector_type(8)));
typedef float f32x4 __attribute__((ext_vector_type(4)));

// ws layout (byte offsets)
#define WS_ENORM  0        // f32[1024]
#define WS_META   4096     // u32[2]: stage1 count, stage2 count
#define WS_RLIST  8192     // u32[32768]
#define WS_RLIST2 139264   // u32[32768]
#define WS_BP     270336   // bf16 frag-order: hi[32 chunks][8192 u16], lo same (+512KB)
#define WS_PB     1318912  // float2[32768][2]
#define WS_PBI    1843200  // u32[32768][2]

#define BP_LO_OFF 262144   // u16 offset of lo region within bp

#define GLOAD_LDS16(g, s)                                                            \
  __builtin_amdgcn_global_load_lds(                                                  \
      (const __attribute__((address_space(1))) unsigned int*)(g),                    \
      (__attribute__((address_space(3))) unsigned int*)(s), 16, 0, 0)

__device__ __forceinline__ unsigned short bf16rne(float x) {
    unsigned u = __float_as_uint(x);
    return (unsigned short)((u + 0x7FFFu + ((u >> 16) & 1u)) >> 16);
}
__device__ __forceinline__ void bf16split(float x, unsigned short& h, unsigned short& l) {
    unsigned u  = __float_as_uint(x);
    unsigned rh = (u + 0x7FFFu + ((u >> 16) & 1u)) & 0xFFFF0000u;   // RNE to bf16
    float    lf = x - __uint_as_float(rh);                          // exact
    h = (unsigned short)(rh >> 16);
    l = bf16rne(lf);
}

// ---------- prep_misc: enorm (fp32 wave-reduce) + meta reset ----------
__global__ __launch_bounds__(256) void prep_misc_kernel(const float* __restrict__ emb,
                                                        float* __restrict__ enorm,
                                                        unsigned* __restrict__ meta) {
    int gid = blockIdx.x * 256 + threadIdx.x;
    if (gid < 2) meta[gid] = 0u;
    int row = gid >> 6, lane = gid & 63;
    float4 v = reinterpret_cast<const float4*>(emb)[(size_t)row * 64 + lane];
    float s = v.x * v.x + v.y * v.y + v.z * v.z + v.w * v.w;
    #pragma unroll
    for (int off = 32; off; off >>= 1) s += __shfl_xor(s, off, 64);
    if (lane == 0) enorm[row] = s;
}

// ---------- prep_b: split emb -> frag-order B', hi region then lo region ----------
// chunk = 32 codes; slot (nf*8+kc); lane (lg*16+lr) holds e[nf*16+lr][kc*32+lg*8..+7]
__global__ __launch_bounds__(256) void prep_b_kernel(const float* __restrict__ emb,
                                                     unsigned short* __restrict__ bp) {
    int tid = blockIdx.x * 256 + threadIdx.x;   // 32768 = 1024 codes x 32
    int j   = tid >> 5;                         // code
    int u   = tid & 31;
    int kc  = u >> 2, lg = u & 3;
    const float* src = emb + (size_t)j * C_DIM + kc * 32 + lg * 8;
    float4 v0 = *reinterpret_cast<const float4*>(src);
    float4 v1 = *reinterpret_cast<const float4*>(src + 4);
    float vs[8] = {v0.x, v0.y, v0.z, v0.w, v1.x, v1.y, v1.z, v1.w};
    unsigned short h[8], l[8];
    #pragma unroll
    for (int k = 0; k < 8; ++k) bf16split(vs[k], h[k], l[k]);
    int chunk = j >> 5, nf = (j >> 4) & 1, lr = j & 15;
    int lane  = lg * 16 + lr;
    size_t base = (size_t)chunk * 8192 + (size_t)(nf * 8 + kc) * 512 + lane * 8;
    uint4 hp, lp;
    hp.x = (unsigned)h[0] | ((unsigned)h[1] << 16);
    hp.y = (unsigned)h[2] | ((unsigned)h[3] << 16);
    hp.z = (unsigned)h[4] | ((unsigned)h[5] << 16);
    hp.w = (unsigned)h[6] | ((unsigned)h[7] << 16);
    lp.x = (unsigned)l[0] | ((unsigned)l[1] << 16);
    lp.y = (unsigned)l[2] | ((unsigned)l[3] << 16);
    lp.z = (unsigned)l[4] | ((unsigned)l[5] << 16);
    lp.w = (unsigned)l[6] | ((unsigned)l[7] << 16);
    *reinterpret_cast<uint4*>(bp + base)             = hp;
    *reinterpret_cast<uint4*>(bp + BP_LO_OFF + base) = lp;
}

// ---------- stage 1: 1-pass hi-only MFMA screen, 4-deep LDS ring ----------
// grid 512 = 256 m-tiles x 2 halves; 256 thr (4 waves x 32 rows).
// A-hi from z in regs. B-hi chunks (32 codes, 16KB) in 4-slot LDS ring staged by
// global_load_lds; 3 chunks (12 loads/thread) kept in flight; vmcnt counted.
__global__ __launch_bounds__(256, 2) void vq_stage1_kernel(
    const float* __restrict__ z, const unsigned short* __restrict__ bp,
    const float* __restrict__ enorm, float2* __restrict__ pb,
    unsigned* __restrict__ pbi) {
    __shared__ unsigned short Bds[4][8192];   // 64 KB ring
    __shared__ float en_s[512];

    const int t = threadIdx.x;
    const int w = t >> 6, lane = t & 63;
    const int lr = lane & 15, lg = lane >> 4;
    const int nh = blockIdx.x & 1;
    const long r0 = (long)(blockIdx.x >> 1) * 128 + w * 32;
    const unsigned short* bsrc = bp + (size_t)(nh * 16) * 8192 + lane * 8;

    en_s[t]       = enorm[nh * 512 + t];
    en_s[t + 256] = enorm[nh * 512 + 256 + t];

    // A: my 32 rows of z, bf16-hi only
    bf16x8 ah[2][8];
    #pragma unroll
    for (int m = 0; m < 2; ++m) {
        const float* zr = z + (r0 + m * 16 + lr) * C_DIM + lg * 8;
        #pragma unroll
        for (int kc = 0; kc < 8; ++kc) {
            float4 v0 = *reinterpret_cast<const float4*>(zr + kc * 32);
            float4 v1 = *reinterpret_cast<const float4*>(zr + kc * 32 + 4);
            float vs[8] = {v0.x, v0.y, v0.z, v0.w, v1.x, v1.y, v1.z, v1.w};
            unsigned hp[4];
            #pragma unroll
            for (int p = 0; p < 4; ++p)
                hp[p] = (unsigned)bf16rne(vs[2 * p]) |
                        ((unsigned)bf16rne(vs[2 * p + 1]) << 16);
            ah[m][kc] = __builtin_bit_cast(bf16x8, *reinterpret_cast<uint4*>(hp));
        }
    }
    __syncthreads();   // en_s visible

#define STG1(c) {                                                       \
    unsigned short* db = &Bds[(c) & 3][0];                              \
    const unsigned short* gs = bsrc + (size_t)(c) * 8192;               \
    _Pragma("unroll") for (int rd = 0; rd < 4; ++rd) {                  \
        int s_ = rd * 4 + w;                                            \
        GLOAD_LDS16(gs + s_ * 512, db + s_ * 512); } }

    STG1(0); STG1(1); STG1(2);   // 12 loads/thread in flight

    float b1[2][4], b2[2][4]; unsigned i1[2][4];
    #pragma unroll
    for (int m = 0; m < 2; ++m)
        #pragma unroll
        for (int r = 0; r < 4; ++r) { b1[m][r] = 3.4e38f; b2[m][r] = 3.4e38f; i1[m][r] = 0; }

    #pragma unroll 1
    for (int c = 0; c < 16; ++c) {
        if (c < 13) {
            STG1(c + 3);   // overwrites buf of chunk c-1; prior trailing BAR ordered readers
            asm volatile("s_waitcnt vmcnt(12)" ::: "memory");  // my chunk-c loads done
        } else if (c == 13) { asm volatile("s_waitcnt vmcnt(8)" ::: "memory"); }
        else if (c == 14)   { asm volatile("s_waitcnt vmcnt(4)" ::: "memory"); }
        else                { asm volatile("s_waitcnt vmcnt(0)" ::: "memory"); }
        __builtin_amdgcn_s_barrier();   // all waves' chunk-c stages complete

        f32x4 a00 = {0.f,0.f,0.f,0.f}, a01 = {0.f,0.f,0.f,0.f};
        f32x4 a10 = {0.f,0.f,0.f,0.f}, a11 = {0.f,0.f,0.f,0.f};
        const unsigned short* bb = &Bds[c & 3][lane * 8];
        #pragma unroll
        for (int kc = 0; kc < 8; ++kc) {
            bf16x8 bh0 = *reinterpret_cast<const bf16x8*>(bb + kc * 512);
            bf16x8 bh1 = *reinterpret_cast<const bf16x8*>(bb + (8 + kc) * 512);
            a00 = __builtin_amdgcn_mfma_f32_16x16x32_bf16(ah[0][kc], bh0, a00, 0, 0, 0);
            a10 = __builtin_amdgcn_mfma_f32_16x16x32_bf16(ah[1][kc], bh0, a10, 0, 0, 0);
            a01 = __builtin_amdgcn_mfma_f32_16x16x32_bf16(ah[0][kc], bh1, a01, 0, 0, 0);
            a11 = __builtin_amdgcn_mfma_f32_16x16x32_bf16(ah[1][kc], bh1, a11, 0, 0, 0);
        }

        // fold chunk into running top-2 (codes ascend per lane -> first-index ties)
        #pragma unroll
        for (int nf = 0; nf < 2; ++nf) {
            const int cl = c * 32 + nf * 16 + lr;
            const float en = en_s[cl];
            const unsigned code = (unsigned)(nh * 512 + cl);
            #pragma unroll
            for (int r = 0; r < 4; ++r) {
                float d0 = fmaf(-2.f, (nf ? a01[r] : a00[r]), en);
                if (d0 < b1[0][r]) { b2[0][r] = b1[0][r]; b1[0][r] = d0; i1[0][r] = code; }
                else if (d0 < b2[0][r]) { b2[0][r] = d0; }
                float d1 = fmaf(-2.f, (nf ? a11[r] : a10[r]), en);
                if (d1 < b1[1][r]) { b2[1][r] = b1[1][r]; b1[1][r] = d1; i1[1][r] = code; }
                else if (d1 < b2[1][r]) { b2[1][r] = d1; }
            }
        }
        __builtin_amdgcn_s_barrier();   // readers of chunk c done (gates next stage)
    }
#undef STG1

    // cross-lane (lr) top-2 merge; write half-partials
    #pragma unroll
    for (int m = 0; m < 2; ++m)
        #pragma unroll
        for (int r = 0; r < 4; ++r) {
            float v1 = b1[m][r], v2 = b2[m][r]; unsigned j1 = i1[m][r];
            #pragma unroll
            for (int off = 8; off; off >>= 1) {
                float    ov1 = __shfl_xor(v1, off, 64);
                float    ov2 = __shfl_xor(v2, off, 64);
                unsigned oj1 = (unsigned)__shfl_xor((int)j1, off, 64);
                if (ov1 < v1 || (ov1 == v1 && oj1 < j1)) {
                    v2 = fminf(v1, ov2); v1 = ov1; j1 = oj1;
                } else {
                    v2 = fminf(v2, ov1);
                }
            }
            if (lr == 0) {
                long row = r0 + m * 16 + lg * 4 + r;
                pb [row * 2 + nh] = make_float2(v1, v2);
                pbi[row * 2 + nh] = j1;
            }
        }
}

// ---------- finalize+gather: merge halves, idx, stage-2 flag, z_q ----------
__global__ __launch_bounds__(256) void finalize_gather_kernel(
    const float* __restrict__ emb, const float2* __restrict__ pb,
    const unsigned* __restrict__ pbi, float* __restrict__ zq,
    float* __restrict__ idx_out, unsigned* __restrict__ meta,
    unsigned* __restrict__ rlist) {
    const long row = (long)blockIdx.x * 4 + (threadIdx.x >> 6);
    const int lane = threadIdx.x & 63;
    float2   p0 = pb [row * 2 + 0], p1 = pb [row * 2 + 1];
    unsigned j0 = pbi[row * 2 + 0], j1 = pbi[row * 2 + 1];
    float B1, B2; unsigned I1;
    if (p1.x < p0.x) { B1 = p1.x; I1 = j1; B2 = fminf(p0.x, p1.y); }
    else             { B1 = p0.x; I1 = j0; B2 = fminf(p0.y, p1.x); }
    if (lane == 0) {
        idx_out[row] = (float)I1;
        if (B2 - B1 <= MARGIN1) rlist[atomicAdd(meta, 1u)] = (unsigned)row;
    }
    float4 v = reinterpret_cast<const float4*>(emb)[(size_t)I1 * 64 + lane];
    reinterpret_cast<float4*>(zq)[row * 64 + lane] = v;   // flagged rows overwritten later
}

// ---------- stage 2: 3-pass split-bf16 re-rank of flagged rows ----------
// grid 256 x 256 thr (4 waves); wave = 16 gathered rows x all 1024 codes,
// reg-direct B (R8-validated inner loop), A split in regs from z.
__global__ __launch_bounds__(256) void vq_stage2_kernel(
    const float* __restrict__ z, const unsigned short* __restrict__ bp,
    const float* __restrict__ enorm, const float* __restrict__ emb,
    const unsigned* __restrict__ meta, const unsigned* __restrict__ rlist,
    float* __restrict__ zq, float* __restrict__ idx_out,
    unsigned* __restrict__ meta2, unsigned* __restrict__ rlist2) {
    __shared__ float en_s[NCODE];
    __shared__ unsigned rows_w[4][16];
    __shared__ unsigned codes_w[4][16];
    const int t = threadIdx.x, w = t >> 6, lane = t & 63;
    const int lr = lane & 15, lg = lane >> 4;
    en_s[t] = enorm[t]; en_s[t + 256] = enorm[t + 256];
    en_s[t + 512] = enorm[t + 512]; en_s[t + 768] = enorm[t + 768];
    __syncthreads();
    const unsigned cnt = meta[0];
    const unsigned wid = blockIdx.x * 4 + (unsigned)w;
    const unsigned stride = gridDim.x * 64;   // waves*16 rows

    for (unsigned base = wid * 16; base < cnt; base += stride) {
        unsigned slot = base + (unsigned)lr;
        unsigned row = rlist[slot < cnt ? slot : 0];
        // A: this row's z, split hi/lo
        bf16x8 ah[8], al[8];
        const float* zr = z + (size_t)row * C_DIM + lg * 8;
        #pragma unroll
        for (int kc = 0; kc < 8; ++kc) {
            float4 v0 = *reinterpret_cast<const float4*>(zr + kc * 32);
            float4 v1 = *reinterpret_cast<const float4*>(zr + kc * 32 + 4);
            float vs[8] = {v0.x, v0.y, v0.z, v0.w, v1.x, v1.y, v1.z, v1.w};
            unsigned short hv[8], lv[8];
            #pragma unroll
            for (int jj = 0; jj < 8; ++jj) bf16split(vs[jj], hv[jj], lv[jj]);
            unsigned hp[4] = {
                (unsigned)hv[0] | ((unsigned)hv[1] << 16), (unsigned)hv[2] | ((unsigned)hv[3] << 16),
                (unsigned)hv[4] | ((unsigned)hv[5] << 16), (unsigned)hv[6] | ((unsigned)hv[7] << 16)};
            unsigned lp[4] = {
                (unsigned)lv[0] | ((unsigned)lv[1] << 16), (unsigned)lv[2] | ((unsigned)lv[3] << 16),
                (unsigned)lv[4] | ((unsigned)lv[5] << 16), (unsigned)lv[6] | ((unsigned)lv[7] << 16)};
            ah[kc] = __builtin_bit_cast(bf16x8, *reinterpret_cast<uint4*>(hp));
            al[kc] = __builtin_bit_cast(bf16x8, *reinterpret_cast<uint4*>(lp));
        }

        float b1[4], b2[4]; unsigned i1[4];
        #pragma unroll
        for (int r = 0; r < 4; ++r) { b1[r] = 3.4e38f; b2[r] = 3.4e38f; i1[r] = 0; }

        for (int c = 0; c < 32; ++c) {
            f32x4 hh0 = {0.f,0.f,0.f,0.f}, hh1 = {0.f,0.f,0.f,0.f};
            f32x4 hl0 = {0.f,0.f,0.f,0.f}, hl1 = {0.f,0.f,0.f,0.f};
            f32x4 lh0 = {0.f,0.f,0.f,0.f}, lh1 = {0.f,0.f,0.f,0.f};
            const unsigned short* cb = bp + (size_t)c * 8192 + lane * 8;
            #pragma unroll
            for (int kc = 0; kc < 8; ++kc) {
                bf16x8 bh0 = *reinterpret_cast<const bf16x8*>(cb + kc * 512);
                bf16x8 bh1 = *reinterpret_cast<const bf16x8*>(cb + (8 + kc) * 512);
                bf16x8 bl0 = *reinterpret_cast<const bf16x8*>(cb + BP_LO_OFF + kc * 512);
                bf16x8 bl1 = *reinterpret_cast<const bf16x8*>(cb + BP_LO_OFF + (8 + kc) * 512);
                hh0 = __builtin_amdgcn_mfma_f32_16x16x32_bf16(ah[kc], bh0, hh0, 0, 0, 0);
                hh1 = __builtin_amdgcn_mfma_f32_16x16x32_bf16(ah[kc], bh1, hh1, 0, 0, 0);
                lh0 = __builtin_amdgcn_mfma_f32_16x16x32_bf16(al[kc], bh0, lh0, 0, 0, 0);
                lh1 = __builtin_amdgcn_mfma_f32_16x16x32_bf16(al[kc], bh1, lh1, 0, 0, 0);
                hl0 = __builtin_amdgcn_mfma_f32_16x16x32_bf16(ah[kc], bl0, hl0, 0, 0, 0);
                hl1 = __builtin_amdgcn_mfma_f32_16x16x32_bf16(ah[kc], bl1, hl1, 0, 0, 0);
            }
            #pragma unroll
            for (int nf = 0; nf < 2; ++nf) {
                const unsigned code = (unsigned)(c * 32 + nf * 16 + lr);
                const float en = en_s[code];
                #pragma unroll
                for (int r = 0; r < 4; ++r) {
                    float s3 = nf ? (hh1[r] + hl1[r] + lh1[r]) : (hh0[r] + hl0[r] + lh0[r]);
                    float d = fmaf(-2.f, s3, en);
                    if (d < b1[r]) { b2[r] = b1[r]; b1[r] = d; i1[r] = code; }
                    else if (d < b2[r]) { b2[r] = d; }
                }
            }
        }

        // cross-lane merge over lr
        #pragma unroll
        for (int r = 0; r < 4; ++r) {
            float v1 = b1[r], v2 = b2[r]; unsigned j1 = i1[r];
            #pragma unroll
            for (int off = 8; off; off >>= 1) {
                float    ov1 = __shfl_xor(v1, off, 64);
                float    ov2 = __shfl_xor(v2, off, 64);
                unsigned oj1 = (unsigned)__shfl_xor((int)j1, off, 64);
                if (ov1 < v1 || (ov1 == v1 && oj1 < j1)) {
                    v2 = fminf(v1, ov2); v1 = ov1; j1 = oj1;
                } else {
                    v2 = fminf(v2, ov1);
                }
            }
            b1[r] = v1; b2[r] = v2; i1[r] = j1;
        }
        if (lr == 0) {
            #pragma unroll
            for (int r = 0; r < 4; ++r) {
                int rs = lg * 4 + r;
                unsigned sl = base + (unsigned)rs;
                if (sl < cnt) {
                    unsigned rrow = rlist[sl];
                    rows_w[w][rs]  = rrow;
                    codes_w[w][rs] = i1[r];
                    idx_out[rrow]  = (float)i1[r];
                    if (b2[r] - b1[r] <= MARGIN2) rlist2[atomicAdd(meta2, 1u)] = rrow;
                } else {
                    rows_w[w][rs] = 0xFFFFFFFFu;
                }
            }
        }
        // gather z_q for this wave's valid rows (intra-wave LDS, compiler waits)
        {
            int rr = lane >> 2, q = lane & 3;
            unsigned rrow = rows_w[w][rr];
            if (rrow != 0xFFFFFFFFu) {
                unsigned code = codes_w[w][rr];
                const float4* ep = reinterpret_cast<const float4*>(emb) + (size_t)code * 64 + q * 16;
                float4*       op = reinterpret_cast<float4*>(zq) + (size_t)rrow * 64 + q * 16;
                #pragma unroll
                for (int j2 = 0; j2 < 16; ++j2) op[j2] = ep[j2];
            }
        }
    }
}

// ---------- rescue: exact fp32 argmin for stage-2 flagged rows ----------
__global__ __launch_bounds__(256) void rescue_kernel(
    const float* __restrict__ z, const float* __restrict__ emb,
    const float* __restrict__ enorm, const unsigned* __restrict__ meta2,
    const unsigned* __restrict__ rlist2, float* __restrict__ zq,
    float* __restrict__ idx_out) {
    __shared__ float zrow[C_DIM];
    __shared__ float rd[256];
    __shared__ unsigned rix[256];
    const unsigned cnt = meta2[0];
    for (unsigned li = blockIdx.x; li < cnt; li += gridDim.x) {
        unsigned row = rlist2[li];
        __syncthreads();
        if (threadIdx.x < 64) {
            float4 v = reinterpret_cast<const float4*>(z)[(size_t)row * 64 + threadIdx.x];
            reinterpret_cast<float4*>(zrow)[threadIdx.x] = v;
        }
        __syncthreads();
        const int c = threadIdx.x;
        float a0 = 0.f, a1 = 0.f, a2 = 0.f, a3 = 0.f;
        const float4* zp = reinterpret_cast<const float4*>(zrow);
        const float4* e0 = reinterpret_cast<const float4*>(emb + (size_t)(c)       * C_DIM);
        const float4* e1 = reinterpret_cast<const float4*>(emb + (size_t)(c + 256) * C_DIM);
        const float4* e2 = reinterpret_cast<const float4*>(emb + (size_t)(c + 512) * C_DIM);
        const float4* e3 = reinterpret_cast<const float4*>(emb + (size_t)(c + 768) * C_DIM);
        #pragma unroll 8
        for (int k = 0; k < 64; ++k) {
            float4 z4 = zp[k];
            float4 f0 = e0[k], f1 = e1[k], f2 = e2[k], f3 = e3[k];
            a0 = fmaf(z4.x, f0.x, a0); a0 = fmaf(z4.y, f0.y, a0);
            a0 = fmaf(z4.z, f0.z, a0); a0 = fmaf(z4.w, f0.w, a0);
            a1 = fmaf(z4.x, f1.x, a1); a1 = fmaf(z4.y, f1.y, a1);
            a1 = fmaf(z4.z, f1.z, a1); a1 = fmaf(z4.w, f1.w, a1);
            a2 = fmaf(z4.x, f2.x, a2); a2 = fmaf(z4.y, f2.y, a2);
            a2 = fmaf(z4.z, f2.z, a2); a2 = fmaf(z4.w, f2.w, a2);
            a3 = fmaf(z4.x, f3.x, a3); a3 = fmaf(z4.y, f3.y, a3);
            a3 = fmaf(z4.z, f3.z, a3); a3 = fmaf(z4.w, f3.w, a3);
        }
        float d0 = fmaf(-2.f, a0, enorm[c]);
        float d1 = fmaf(-2.f, a1, enorm[c + 256]);
        float d2 = fmaf(-2.f, a2, enorm[c + 512]);
        float d3 = fmaf(-2.f, a3, enorm[c + 768]);
        float bd = d0; unsigned bi = (unsigned)c;
        if (d1 < bd) { bd = d1; bi = (unsigned)(c + 256); }
        if (d2 < bd) { bd = d2; bi = (unsigned)(c + 512); }
        if (d3 < bd) { bd = d3; bi = (unsigned)(c + 768); }
        rd[threadIdx.x] = bd; rix[threadIdx.x] = bi;
        __syncthreads();
        for (int s = 128; s; s >>= 1) {
            if (threadIdx.x < (unsigned)s) {
                float od = rd[threadIdx.x + s]; unsigned oi = rix[threadIdx.x + s];
                if (od < rd[threadIdx.x] ||
                    (od == rd[threadIdx.x] && oi < rix[threadIdx.x])) {
                    rd[threadIdx.x] = od; rix[threadIdx.x] = oi;
                }
            }
            __syncthreads();
        }
        unsigned code = rix[0];
        if (threadIdx.x < 64) {
            float4 v = reinterpret_cast<const float4*>(emb)[(size_t)code * 64 + threadIdx.x];
            reinterpret_cast<float4*>(zq)[(size_t)row * 64 + threadIdx.x] = v;
        }
        if (threadIdx.x == 0) idx_out[row] = (float)code;
    }
}

extern "C" void kernel_launch(void* const* d_in, const int* in_sizes, int n_in,
                              void* d_out, int out_size, void* d_ws, size_t ws_size,
                              hipStream_t stream) {
    const float* z   = (const float*)d_in[0];
    const float* emb = (const float*)d_in[1];
    const int n = in_sizes[0] / C_DIM;   // 32768

    float* zq      = (float*)d_out;
    float* idx_out = zq + (size_t)n * C_DIM;

    char* ws = (char*)d_ws;
    float*          enorm  = (float*)(ws + WS_ENORM);
    unsigned*       meta   = (unsigned*)(ws + WS_META);
    unsigned*       rlist  = (unsigned*)(ws + WS_RLIST);
    unsigned*       rlist2 = (unsigned*)(ws + WS_RLIST2);
    unsigned short* bp     = (unsigned short*)(ws + WS_BP);
    float2*         pb     = (float2*)(ws + WS_PB);
    unsigned*       pbi    = (unsigned*)(ws + WS_PBI);

    prep_misc_kernel<<<256, 256, 0, stream>>>(emb, enorm, meta);
    prep_b_kernel<<<128, 256, 0, stream>>>(emb, bp);
    vq_stage1_kernel<<<(n / 128) * 2, 256, 0, stream>>>(z, bp, enorm, pb, pbi);
    finalize_gather_kernel<<<n / 4, 256, 0, stream>>>(emb, pb, pbi, zq, idx_out,
                                                      meta, rlist);
    vq_stage2_kernel<<<256, 256, 0, stream>>>(z, bp, enorm, emb, meta, rlist,
                                              zq, idx_out, meta + 1, rlist2);
    rescue_kernel<<<256, 256, 0, stream>>>(z, emb, enorm, meta + 1, rlist2,
                                           zq, idx_out);
}

// Round 12
// 137.311 us; speedup vs baseline: 1.5967x; 1.5967x over previous
//
#include <hip/hip_runtime.h>

#define C_DIM 256
#define NCODE 1024
#define MARGIN1 0.35f   // stage-1 screen (1-pass err-diff sigma ~0.07 -> 5 sigma)
#define MARGIN2 0.02f   // stage-2 screen (3-pass, validated R5+)

typedef __bf16 bf16x8 __attribute__((ext_vector_type(8)));
typedef float f32x4 __attribute__((ext_vector_type(4)));

// ws layout (byte offsets)
#define WS_ENORM  0        // f32[1024]
#define WS_META   4096     // u32[2]: stage1 count, stage2 count
#define WS_RLIST  8192     // u32[32768]
#define WS_RLIST2 139264   // u32[32768]
#define WS_BP     270336   // bf16 frag-order: hi[32 chunks][8192 u16], lo same (+512KB)
#define WS_PB     1318912  // float2[32768][2]  (stage-1 half partials)
#define WS_PBI    1843200  // u32[32768][2]
#define WS_PB2    2105344  // float2[32768][4]  (stage-2 quarter partials, by slot)
#define WS_PBI2   3153920  // u32[32768][4]

#define BP_LO_OFF 262144   // u16 offset of lo region within bp

#define GLOAD_LDS16(g, s)                                                            \
  __builtin_amdgcn_global_load_lds(                                                  \
      (const __attribute__((address_space(1))) unsigned int*)(g),                    \
      (__attribute__((address_space(3))) unsigned int*)(s), 16, 0, 0)

__device__ __forceinline__ unsigned short bf16rne(float x) {
    unsigned u = __float_as_uint(x);
    return (unsigned short)((u + 0x7FFFu + ((u >> 16) & 1u)) >> 16);
}
__device__ __forceinline__ void bf16split(float x, unsigned short& h, unsigned short& l) {
    unsigned u  = __float_as_uint(x);
    unsigned rh = (u + 0x7FFFu + ((u >> 16) & 1u)) & 0xFFFF0000u;   // RNE to bf16
    float    lf = x - __uint_as_float(rh);                          // exact
    h = (unsigned short)(rh >> 16);
    l = bf16rne(lf);
}

// ---------- prep_misc: enorm (fp32 wave-reduce) + meta reset ----------
__global__ __launch_bounds__(256) void prep_misc_kernel(const float* __restrict__ emb,
                                                        float* __restrict__ enorm,
                                                        unsigned* __restrict__ meta) {
    int gid = blockIdx.x * 256 + threadIdx.x;
    if (gid < 2) meta[gid] = 0u;
    int row = gid >> 6, lane = gid & 63;
    float4 v = reinterpret_cast<const float4*>(emb)[(size_t)row * 64 + lane];
    float s = v.x * v.x + v.y * v.y + v.z * v.z + v.w * v.w;
    #pragma unroll
    for (int off = 32; off; off >>= 1) s += __shfl_xor(s, off, 64);
    if (lane == 0) enorm[row] = s;
}

// ---------- prep_b: split emb -> frag-order B', hi region then lo region ----------
__global__ __launch_bounds__(256) void prep_b_kernel(const float* __restrict__ emb,
                                                     unsigned short* __restrict__ bp) {
    int tid = blockIdx.x * 256 + threadIdx.x;   // 32768 = 1024 codes x 32
    int j   = tid >> 5;                         // code
    int u   = tid & 31;
    int kc  = u >> 2, lg = u & 3;
    const float* src = emb + (size_t)j * C_DIM + kc * 32 + lg * 8;
    float4 v0 = *reinterpret_cast<const float4*>(src);
    float4 v1 = *reinterpret_cast<const float4*>(src + 4);
    float vs[8] = {v0.x, v0.y, v0.z, v0.w, v1.x, v1.y, v1.z, v1.w};
    unsigned short h[8], l[8];
    #pragma unroll
    for (int k = 0; k < 8; ++k) bf16split(vs[k], h[k], l[k]);
    int chunk = j >> 5, nf = (j >> 4) & 1, lr = j & 15;
    int lane  = lg * 16 + lr;
    size_t base = (size_t)chunk * 8192 + (size_t)(nf * 8 + kc) * 512 + lane * 8;
    uint4 hp, lp;
    hp.x = (unsigned)h[0] | ((unsigned)h[1] << 16);
    hp.y = (unsigned)h[2] | ((unsigned)h[3] << 16);
    hp.z = (unsigned)h[4] | ((unsigned)h[5] << 16);
    hp.w = (unsigned)h[6] | ((unsigned)h[7] << 16);
    lp.x = (unsigned)l[0] | ((unsigned)l[1] << 16);
    lp.y = (unsigned)l[2] | ((unsigned)l[3] << 16);
    lp.z = (unsigned)l[4] | ((unsigned)l[5] << 16);
    lp.w = (unsigned)l[6] | ((unsigned)l[7] << 16);
    *reinterpret_cast<uint4*>(bp + base)             = hp;
    *reinterpret_cast<uint4*>(bp + BP_LO_OFF + base) = lp;
}

// ---------- stage 1: 1-pass hi-only MFMA screen, 4-deep LDS ring ----------
__global__ __launch_bounds__(256, 2) void vq_stage1_kernel(
    const float* __restrict__ z, const unsigned short* __restrict__ bp,
    const float* __restrict__ enorm, float2* __restrict__ pb,
    unsigned* __restrict__ pbi) {
    __shared__ unsigned short Bds[4][8192];   // 64 KB ring
    __shared__ float en_s[512];

    const int t = threadIdx.x;
    const int w = t >> 6, lane = t & 63;
    const int lr = lane & 15, lg = lane >> 4;
    const int nh = blockIdx.x & 1;
    const long r0 = (long)(blockIdx.x >> 1) * 128 + w * 32;
    const unsigned short* bsrc = bp + (size_t)(nh * 16) * 8192 + lane * 8;

    en_s[t]       = enorm[nh * 512 + t];
    en_s[t + 256] = enorm[nh * 512 + 256 + t];

    bf16x8 ah[2][8];
    #pragma unroll
    for (int m = 0; m < 2; ++m) {
        const float* zr = z + (r0 + m * 16 + lr) * C_DIM + lg * 8;
        #pragma unroll
        for (int kc = 0; kc < 8; ++kc) {
            float4 v0 = *reinterpret_cast<const float4*>(zr + kc * 32);
            float4 v1 = *reinterpret_cast<const float4*>(zr + kc * 32 + 4);
            float vs[8] = {v0.x, v0.y, v0.z, v0.w, v1.x, v1.y, v1.z, v1.w};
            unsigned hp[4];
            #pragma unroll
            for (int p = 0; p < 4; ++p)
                hp[p] = (unsigned)bf16rne(vs[2 * p]) |
                        ((unsigned)bf16rne(vs[2 * p + 1]) << 16);
            ah[m][kc] = __builtin_bit_cast(bf16x8, *reinterpret_cast<uint4*>(hp));
        }
    }
    __syncthreads();   // en_s visible

#define STG1(c) {                                                       \
    unsigned short* db = &Bds[(c) & 3][0];                              \
    const unsigned short* gs = bsrc + (size_t)(c) * 8192;               \
    _Pragma("unroll") for (int rd = 0; rd < 4; ++rd) {                  \
        int s_ = rd * 4 + w;                                            \
        GLOAD_LDS16(gs + s_ * 512, db + s_ * 512); } }

    STG1(0); STG1(1); STG1(2);   // 12 loads/thread in flight

    float b1[2][4], b2[2][4]; unsigned i1[2][4];
    #pragma unroll
    for (int m = 0; m < 2; ++m)
        #pragma unroll
        for (int r = 0; r < 4; ++r) { b1[m][r] = 3.4e38f; b2[m][r] = 3.4e38f; i1[m][r] = 0; }

    #pragma unroll 1
    for (int c = 0; c < 16; ++c) {
        if (c < 13) {
            STG1(c + 3);
            asm volatile("s_waitcnt vmcnt(12)" ::: "memory");
        } else if (c == 13) { asm volatile("s_waitcnt vmcnt(8)" ::: "memory"); }
        else if (c == 14)   { asm volatile("s_waitcnt vmcnt(4)" ::: "memory"); }
        else                { asm volatile("s_waitcnt vmcnt(0)" ::: "memory"); }
        __builtin_amdgcn_s_barrier();

        f32x4 a00 = {0.f,0.f,0.f,0.f}, a01 = {0.f,0.f,0.f,0.f};
        f32x4 a10 = {0.f,0.f,0.f,0.f}, a11 = {0.f,0.f,0.f,0.f};
        const unsigned short* bb = &Bds[c & 3][lane * 8];
        #pragma unroll
        for (int kc = 0; kc < 8; ++kc) {
            bf16x8 bh0 = *reinterpret_cast<const bf16x8*>(bb + kc * 512);
            bf16x8 bh1 = *reinterpret_cast<const bf16x8*>(bb + (8 + kc) * 512);
            a00 = __builtin_amdgcn_mfma_f32_16x16x32_bf16(ah[0][kc], bh0, a00, 0, 0, 0);
            a10 = __builtin_amdgcn_mfma_f32_16x16x32_bf16(ah[1][kc], bh0, a10, 0, 0, 0);
            a01 = __builtin_amdgcn_mfma_f32_16x16x32_bf16(ah[0][kc], bh1, a01, 0, 0, 0);
            a11 = __builtin_amdgcn_mfma_f32_16x16x32_bf16(ah[1][kc], bh1, a11, 0, 0, 0);
        }

        #pragma unroll
        for (int nf = 0; nf < 2; ++nf) {
            const int cl = c * 32 + nf * 16 + lr;
            const float en = en_s[cl];
            const unsigned code = (unsigned)(nh * 512 + cl);
            #pragma unroll
            for (int r = 0; r < 4; ++r) {
                float d0 = fmaf(-2.f, (nf ? a01[r] : a00[r]), en);
                if (d0 < b1[0][r]) { b2[0][r] = b1[0][r]; b1[0][r] = d0; i1[0][r] = code; }
                else if (d0 < b2[0][r]) { b2[0][r] = d0; }
                float d1 = fmaf(-2.f, (nf ? a11[r] : a10[r]), en);
                if (d1 < b1[1][r]) { b2[1][r] = b1[1][r]; b1[1][r] = d1; i1[1][r] = code; }
                else if (d1 < b2[1][r]) { b2[1][r] = d1; }
            }
        }
        __builtin_amdgcn_s_barrier();
    }
#undef STG1

    #pragma unroll
    for (int m = 0; m < 2; ++m)
        #pragma unroll
        for (int r = 0; r < 4; ++r) {
            float v1 = b1[m][r], v2 = b2[m][r]; unsigned j1 = i1[m][r];
            #pragma unroll
            for (int off = 8; off; off >>= 1) {
                float    ov1 = __shfl_xor(v1, off, 64);
                float    ov2 = __shfl_xor(v2, off, 64);
                unsigned oj1 = (unsigned)__shfl_xor((int)j1, off, 64);
                if (ov1 < v1 || (ov1 == v1 && oj1 < j1)) {
                    v2 = fminf(v1, ov2); v1 = ov1; j1 = oj1;
                } else {
                    v2 = fminf(v2, ov1);
                }
            }
            if (lr == 0) {
                long row = r0 + m * 16 + lg * 4 + r;
                pb [row * 2 + nh] = make_float2(v1, v2);
                pbi[row * 2 + nh] = j1;
            }
        }
}

// ---------- finalize+gather: merge halves, idx, stage-2 flag, z_q ----------
__global__ __launch_bounds__(256) void finalize_gather_kernel(
    const float* __restrict__ emb, const float2* __restrict__ pb,
    const unsigned* __restrict__ pbi, float* __restrict__ zq,
    float* __restrict__ idx_out, unsigned* __restrict__ meta,
    unsigned* __restrict__ rlist) {
    const long row = (long)blockIdx.x * 4 + (threadIdx.x >> 6);
    const int lane = threadIdx.x & 63;
    float2   p0 = pb [row * 2 + 0], p1 = pb [row * 2 + 1];
    unsigned j0 = pbi[row * 2 + 0], j1 = pbi[row * 2 + 1];
    float B1, B2; unsigned I1;
    if (p1.x < p0.x) { B1 = p1.x; I1 = j1; B2 = fminf(p0.x, p1.y); }
    else             { B1 = p0.x; I1 = j0; B2 = fminf(p0.y, p1.x); }
    if (lane == 0) {
        idx_out[row] = (float)I1;
        if (B2 - B1 <= MARGIN1) rlist[atomicAdd(meta, 1u)] = (unsigned)row;
    }
    float4 v = reinterpret_cast<const float4*>(emb)[(size_t)I1 * 64 + lane];
    reinterpret_cast<float4*>(zq)[row * 64 + lane] = v;   // flagged rows overwritten later
}

// ---------- stage 2: 3-pass re-rank, item = (16-row group) x (256-code quarter) ----------
// grid 512 x 256 (4 waves). Block handles 4 consecutive items = same row-group,
// all 4 quarters (A rows shared via L1). Partials written per (slot, quarter).
__global__ __launch_bounds__(256) void vq_stage2_kernel(
    const float* __restrict__ z, const unsigned short* __restrict__ bp,
    const float* __restrict__ enorm, const unsigned* __restrict__ meta,
    const unsigned* __restrict__ rlist, float2* __restrict__ pb2,
    unsigned* __restrict__ pbi2) {
    __shared__ float en_s[NCODE];
    const int t = threadIdx.x, w = t >> 6, lane = t & 63;
    const int lr = lane & 15, lg = lane >> 4;
    en_s[t] = enorm[t]; en_s[t + 256] = enorm[t + 256];
    en_s[t + 512] = enorm[t + 512]; en_s[t + 768] = enorm[t + 768];
    __syncthreads();
    const unsigned cnt = meta[0];
    const unsigned nitems = ((cnt + 15) >> 4) << 2;   // groups * 4 quarters

    for (unsigned item = blockIdx.x * 4 + (unsigned)w; item < nitems;
         item += gridDim.x * 4) {
        const unsigned g = item >> 2, q = item & 3;
        const unsigned base = g * 16;
        unsigned slot = base + (unsigned)lr;
        unsigned row = rlist[slot < cnt ? slot : 0];

        // A: this row's z, split hi/lo
        bf16x8 ah[8], al[8];
        const float* zr = z + (size_t)row * C_DIM + lg * 8;
        #pragma unroll
        for (int kc = 0; kc < 8; ++kc) {
            float4 v0 = *reinterpret_cast<const float4*>(zr + kc * 32);
            float4 v1 = *reinterpret_cast<const float4*>(zr + kc * 32 + 4);
            float vs[8] = {v0.x, v0.y, v0.z, v0.w, v1.x, v1.y, v1.z, v1.w};
            unsigned short hv[8], lv[8];
            #pragma unroll
            for (int jj = 0; jj < 8; ++jj) bf16split(vs[jj], hv[jj], lv[jj]);
            unsigned hp[4] = {
                (unsigned)hv[0] | ((unsigned)hv[1] << 16), (unsigned)hv[2] | ((unsigned)hv[3] << 16),
                (unsigned)hv[4] | ((unsigned)hv[5] << 16), (unsigned)hv[6] | ((unsigned)hv[7] << 16)};
            unsigned lp[4] = {
                (unsigned)lv[0] | ((unsigned)lv[1] << 16), (unsigned)lv[2] | ((unsigned)lv[3] << 16),
                (unsigned)lv[4] | ((unsigned)lv[5] << 16), (unsigned)lv[6] | ((unsigned)lv[7] << 16)};
            ah[kc] = __builtin_bit_cast(bf16x8, *reinterpret_cast<uint4*>(hp));
            al[kc] = __builtin_bit_cast(bf16x8, *reinterpret_cast<uint4*>(lp));
        }

        float b1[4], b2[4]; unsigned i1[4];
        #pragma unroll
        for (int r = 0; r < 4; ++r) { b1[r] = 3.4e38f; b2[r] = 3.4e38f; i1[r] = 0; }

        #pragma unroll 1
        for (int cc = 0; cc < 8; ++cc) {
            const int c = (int)q * 8 + cc;
            f32x4 hh0 = {0.f,0.f,0.f,0.f}, hh1 = {0.f,0.f,0.f,0.f};
            f32x4 hl0 = {0.f,0.f,0.f,0.f}, hl1 = {0.f,0.f,0.f,0.f};
            f32x4 lh0 = {0.f,0.f,0.f,0.f}, lh1 = {0.f,0.f,0.f,0.f};
            const unsigned short* cb = bp + (size_t)c * 8192 + lane * 8;
            #pragma unroll
            for (int kc = 0; kc < 8; ++kc) {
                bf16x8 bh0 = *reinterpret_cast<const bf16x8*>(cb + kc * 512);
                bf16x8 bh1 = *reinterpret_cast<const bf16x8*>(cb + (8 + kc) * 512);
                bf16x8 bl0 = *reinterpret_cast<const bf16x8*>(cb + BP_LO_OFF + kc * 512);
                bf16x8 bl1 = *reinterpret_cast<const bf16x8*>(cb + BP_LO_OFF + (8 + kc) * 512);
                hh0 = __builtin_amdgcn_mfma_f32_16x16x32_bf16(ah[kc], bh0, hh0, 0, 0, 0);
                hh1 = __builtin_amdgcn_mfma_f32_16x16x32_bf16(ah[kc], bh1, hh1, 0, 0, 0);
                lh0 = __builtin_amdgcn_mfma_f32_16x16x32_bf16(al[kc], bh0, lh0, 0, 0, 0);
                lh1 = __builtin_amdgcn_mfma_f32_16x16x32_bf16(al[kc], bh1, lh1, 0, 0, 0);
                hl0 = __builtin_amdgcn_mfma_f32_16x16x32_bf16(ah[kc], bl0, hl0, 0, 0, 0);
                hl1 = __builtin_amdgcn_mfma_f32_16x16x32_bf16(ah[kc], bl1, hl1, 0, 0, 0);
            }
            #pragma unroll
            for (int nf = 0; nf < 2; ++nf) {
                const unsigned code = (unsigned)(c * 32 + nf * 16 + lr);
                const float en = en_s[code];
                #pragma unroll
                for (int r = 0; r < 4; ++r) {
                    float s3 = nf ? (hh1[r] + hl1[r] + lh1[r]) : (hh0[r] + hl0[r] + lh0[r]);
                    float d = fmaf(-2.f, s3, en);
                    if (d < b1[r]) { b2[r] = b1[r]; b1[r] = d; i1[r] = code; }
                    else if (d < b2[r]) { b2[r] = d; }
                }
            }
        }

        // cross-lane merge over lr, write quarter partials
        #pragma unroll
        for (int r = 0; r < 4; ++r) {
            float v1 = b1[r], v2 = b2[r]; unsigned j1 = i1[r];
            #pragma unroll
            for (int off = 8; off; off >>= 1) {
                float    ov1 = __shfl_xor(v1, off, 64);
                float    ov2 = __shfl_xor(v2, off, 64);
                unsigned oj1 = (unsigned)__shfl_xor((int)j1, off, 64);
                if (ov1 < v1 || (ov1 == v1 && oj1 < j1)) {
                    v2 = fminf(v1, ov2); v1 = ov1; j1 = oj1;
                } else {
                    v2 = fminf(v2, ov1);
                }
            }
            if (lr == 0) {
                unsigned sl = base + (unsigned)(lg * 4 + r);
                if (sl < cnt) {
                    pb2 [sl * 4 + q] = make_float2(v1, v2);
                    pbi2[sl * 4 + q] = j1;
                }
            }
        }
    }
}

// ---------- finalize2: merge 4 quarters per flagged row, idx + z_q + rescue flag ----------
__global__ __launch_bounds__(256) void finalize2_kernel(
    const float* __restrict__ emb, const unsigned* __restrict__ meta,
    const unsigned* __restrict__ rlist, const float2* __restrict__ pb2,
    const unsigned* __restrict__ pbi2, float* __restrict__ zq,
    float* __restrict__ idx_out, unsigned* __restrict__ meta2,
    unsigned* __restrict__ rlist2) {
    const int w = threadIdx.x >> 6, lane = threadIdx.x & 63;
    const unsigned cnt = meta[0];
    for (unsigned slot = blockIdx.x * 4 + (unsigned)w; slot < cnt;
         slot += gridDim.x * 4) {
        unsigned row = rlist[slot];
        float B1 = 3.4e38f, B2 = 3.4e38f; unsigned I1 = 0;
        #pragma unroll
        for (int s = 0; s < 4; ++s) {   // ascending quarter = ascending codes
            float2   p = pb2 [slot * 4 + s];
            unsigned j = pbi2[slot * 4 + s];
            if (p.x < B1) { B2 = fminf(B1, p.y); B1 = p.x; I1 = j; }
            else          { B2 = fminf(B2, p.x); }
        }
        if (lane == 0) {
            idx_out[row] = (float)I1;
            if (B2 - B1 <= MARGIN2) rlist2[atomicAdd(meta2, 1u)] = row;
        }
        float4 v = reinterpret_cast<const float4*>(emb)[(size_t)I1 * 64 + lane];
        reinterpret_cast<float4*>(zq)[(size_t)row * 64 + lane] = v;
    }
}

// ---------- rescue: exact fp32 argmin for stage-2 flagged rows ----------
__global__ __launch_bounds__(256) void rescue_kernel(
    const float* __restrict__ z, const float* __restrict__ emb,
    const float* __restrict__ enorm, const unsigned* __restrict__ meta2,
    const unsigned* __restrict__ rlist2, float* __restrict__ zq,
    float* __restrict__ idx_out) {
    __shared__ float zrow[C_DIM];
    __shared__ float rd[256];
    __shared__ unsigned rix[256];
    const unsigned cnt = meta2[0];
    for (unsigned li = blockIdx.x; li < cnt; li += gridDim.x) {
        unsigned row = rlist2[li];
        __syncthreads();
        if (threadIdx.x < 64) {
            float4 v = reinterpret_cast<const float4*>(z)[(size_t)row * 64 + threadIdx.x];
            reinterpret_cast<float4*>(zrow)[threadIdx.x] = v;
        }
        __syncthreads();
        const int c = threadIdx.x;
        float a0 = 0.f, a1 = 0.f, a2 = 0.f, a3 = 0.f;
        const float4* zp = reinterpret_cast<const float4*>(zrow);
        const float4* e0 = reinterpret_cast<const float4*>(emb + (size_t)(c)       * C_DIM);
        const float4* e1 = reinterpret_cast<const float4*>(emb + (size_t)(c + 256) * C_DIM);
        const float4* e2 = reinterpret_cast<const float4*>(emb + (size_t)(c + 512) * C_DIM);
        const float4* e3 = reinterpret_cast<const float4*>(emb + (size_t)(c + 768) * C_DIM);
        #pragma unroll 8
        for (int k = 0; k < 64; ++k) {
            float4 z4 = zp[k];
            float4 f0 = e0[k], f1 = e1[k], f2 = e2[k], f3 = e3[k];
            a0 = fmaf(z4.x, f0.x, a0); a0 = fmaf(z4.y, f0.y, a0);
            a0 = fmaf(z4.z, f0.z, a0); a0 = fmaf(z4.w, f0.w, a0);
            a1 = fmaf(z4.x, f1.x, a1); a1 = fmaf(z4.y, f1.y, a1);
            a1 = fmaf(z4.z, f1.z, a1); a1 = fmaf(z4.w, f1.w, a1);
            a2 = fmaf(z4.x, f2.x, a2); a2 = fmaf(z4.y, f2.y, a2);
            a2 = fmaf(z4.z, f2.z, a2); a2 = fmaf(z4.w, f2.w, a2);
            a3 = fmaf(z4.x, f3.x, a3); a3 = fmaf(z4.y, f3.y, a3);
            a3 = fmaf(z4.z, f3.z, a3); a3 = fmaf(z4.w, f3.w, a3);
        }
        float d0 = fmaf(-2.f, a0, enorm[c]);
        float d1 = fmaf(-2.f, a1, enorm[c + 256]);
        float d2 = fmaf(-2.f, a2, enorm[c + 512]);
        float d3 = fmaf(-2.f, a3, enorm[c + 768]);
        float bd = d0; unsigned bi = (unsigned)c;
        if (d1 < bd) { bd = d1; bi = (unsigned)(c + 256); }
        if (d2 < bd) { bd = d2; bi = (unsigned)(c + 512); }
        if (d3 < bd) { bd = d3; bi = (unsigned)(c + 768); }
        rd[threadIdx.x] = bd; rix[threadIdx.x] = bi;
        __syncthreads();
        for (int s = 128; s; s >>= 1) {
            if (threadIdx.x < (unsigned)s) {
                float od = rd[threadIdx.x + s]; unsigned oi = rix[threadIdx.x + s];
                if (od < rd[threadIdx.x] ||
                    (od == rd[threadIdx.x] && oi < rix[threadIdx.x])) {
                    rd[threadIdx.x] = od; rix[threadIdx.x] = oi;
                }
            }
            __syncthreads();
        }
        unsigned code = rix[0];
        if (threadIdx.x < 64) {
            float4 v = reinterpret_cast<const float4*>(emb)[(size_t)code * 64 + threadIdx.x];
            reinterpret_cast<float4*>(zq)[(size_t)row * 64 + threadIdx.x] = v;
        }
        if (threadIdx.x == 0) idx_out[row] = (float)code;
    }
}

extern "C" void kernel_launch(void* const* d_in, const int* in_sizes, int n_in,
                              void* d_out, int out_size, void* d_ws, size_t ws_size,
                              hipStream_t stream) {
    const float* z   = (const float*)d_in[0];
    const float* emb = (const float*)d_in[1];
    const int n = in_sizes[0] / C_DIM;   // 32768

    float* zq      = (float*)d_out;
    float* idx_out = zq + (size_t)n * C_DIM;

    char* ws = (char*)d_ws;
    float*          enorm  = (float*)(ws + WS_ENORM);
    unsigned*       meta   = (unsigned*)(ws + WS_META);
    unsigned*       rlist  = (unsigned*)(ws + WS_RLIST);
    unsigned*       rlist2 = (unsigned*)(ws + WS_RLIST2);
    unsigned short* bp     = (unsigned short*)(ws + WS_BP);
    float2*         pb     = (float2*)(ws + WS_PB);
    unsigned*       pbi    = (unsigned*)(ws + WS_PBI);
    float2*         pb2    = (float2*)(ws + WS_PB2);
    unsigned*       pbi2   = (unsigned*)(ws + WS_PBI2);

    prep_misc_kernel<<<256, 256, 0, stream>>>(emb, enorm, meta);
    prep_b_kernel<<<128, 256, 0, stream>>>(emb, bp);
    vq_stage1_kernel<<<(n / 128) * 2, 256, 0, stream>>>(z, bp, enorm, pb, pbi);
    finalize_gather_kernel<<<n / 4, 256, 0, stream>>>(emb, pb, pbi, zq, idx_out,
                                                      meta, rlist);
    vq_stage2_kernel<<<512, 256, 0, stream>>>(z, bp, enorm, meta, rlist, pb2, pbi2);
    finalize2_kernel<<<512, 256, 0, stream>>>(emb, meta, rlist, pb2, pbi2,
                                              zq, idx_out, meta + 1, rlist2);
    rescue_kernel<<<256, 256, 0, stream>>>(z, emb, enorm, meta + 1, rlist2,
                                           zq, idx_out);
}

// Round 13
// 134.091 us; speedup vs baseline: 1.6350x; 1.0240x over previous
//
#include <hip/hip_runtime.h>

#define C_DIM 256
#define NCODE 1024
#define MARGIN1 0.35f   // stage-1 screen (1-pass err-diff sigma ~0.07 -> 5 sigma)
#define MARGIN2 0.02f   // stage-2 screen (3-pass, validated R5+)

typedef __bf16 bf16x8 __attribute__((ext_vector_type(8)));
typedef float f32x4 __attribute__((ext_vector_type(4)));

// ws layout (byte offsets)
#define WS_ENORM  0        // f32[1024]
#define WS_META   4096     // u32[2]: stage1 count, stage2 count
#define WS_RLIST  8192     // u32[32768]
#define WS_RLIST2 139264   // u32[32768]
#define WS_BP     270336   // bf16 frag-order: hi[32 chunks][8192 u16], lo same (+512KB)
#define WS_PB     1318912  // float2[32768][2]  (stage-1 half partials)
#define WS_PBI    1843200  // u32[32768][2]
#define WS_PB2    2105344  // float2[32768][4]  (stage-2 quarter partials, by slot)
#define WS_PBI2   3153920  // u32[32768][4]

#define BP_LO_OFF 262144   // u16 offset of lo region within bp

#define GLOAD_LDS16(g, s)                                                            \
  __builtin_amdgcn_global_load_lds(                                                  \
      (const __attribute__((address_space(1))) unsigned int*)(g),                    \
      (__attribute__((address_space(3))) unsigned int*)(s), 16, 0, 0)

__device__ __forceinline__ unsigned short bf16rne(float x) {
    unsigned u = __float_as_uint(x);
    return (unsigned short)((u + 0x7FFFu + ((u >> 16) & 1u)) >> 16);
}
__device__ __forceinline__ void bf16split(float x, unsigned short& h, unsigned short& l) {
    unsigned u  = __float_as_uint(x);
    unsigned rh = (u + 0x7FFFu + ((u >> 16) & 1u)) & 0xFFFF0000u;   // RNE to bf16
    float    lf = x - __uint_as_float(rh);                          // exact
    h = (unsigned short)(rh >> 16);
    l = bf16rne(lf);
}

// ---------- prep: emb -> frag-order B' (hi|lo) + enorm + meta reset (fused) ----------
// 32 threads per code: kc = u>>2 (k/32), lg = u&3 (8-elem group). Each thread
// also accumulates its 8 elems' squares; 32-lane xor-shuffle reduce -> enorm.
__global__ __launch_bounds__(256) void prep_kernel(const float* __restrict__ emb,
                                                   unsigned short* __restrict__ bp,
                                                   float* __restrict__ enorm,
                                                   unsigned* __restrict__ meta) {
    int tid = blockIdx.x * 256 + threadIdx.x;   // 32768 = 1024 codes x 32
    if (tid < 2) meta[tid] = 0u;
    int j   = tid >> 5;                         // code
    int u   = tid & 31;
    int kc  = u >> 2, lg = u & 3;
    const float* src = emb + (size_t)j * C_DIM + kc * 32 + lg * 8;
    float4 v0 = *reinterpret_cast<const float4*>(src);
    float4 v1 = *reinterpret_cast<const float4*>(src + 4);
    float vs[8] = {v0.x, v0.y, v0.z, v0.w, v1.x, v1.y, v1.z, v1.w};
    unsigned short h[8], l[8];
    float s = 0.f;
    #pragma unroll
    for (int k = 0; k < 8; ++k) {
        bf16split(vs[k], h[k], l[k]);
        s = fmaf(vs[k], vs[k], s);
    }
    // reduce over the 32 threads of this code (xor on lane bits 0..4 stays in-group)
    #pragma unroll
    for (int off = 1; off < 32; off <<= 1) s += __shfl_xor(s, off, 64);
    if (u == 0) enorm[j] = s;

    int chunk = j >> 5, nf = (j >> 4) & 1, lr = j & 15;
    int lane  = lg * 16 + lr;
    size_t base = (size_t)chunk * 8192 + (size_t)(nf * 8 + kc) * 512 + lane * 8;
    uint4 hp, lp;
    hp.x = (unsigned)h[0] | ((unsigned)h[1] << 16);
    hp.y = (unsigned)h[2] | ((unsigned)h[3] << 16);
    hp.z = (unsigned)h[4] | ((unsigned)h[5] << 16);
    hp.w = (unsigned)h[6] | ((unsigned)h[7] << 16);
    lp.x = (unsigned)l[0] | ((unsigned)l[1] << 16);
    lp.y = (unsigned)l[2] | ((unsigned)l[3] << 16);
    lp.z = (unsigned)l[4] | ((unsigned)l[5] << 16);
    lp.w = (unsigned)l[6] | ((unsigned)l[7] << 16);
    *reinterpret_cast<uint4*>(bp + base)             = hp;
    *reinterpret_cast<uint4*>(bp + BP_LO_OFF + base) = lp;
}

// ---------- stage 1: 1-pass hi-only MFMA screen, 4-deep ring, 1 barrier/chunk ----------
// iter c: {vmcnt(8): my chunk-c loads landed} -> s_barrier {all waves' chunk-c
// visible AND all waves done reading chunk c-1} -> STG(c+3) into slot (c-1)&3
// (safe: just proven idle) -> compute chunk c. Loads for c+1..c+3 stay in
// flight across the barrier (counted vmcnt, T4).
__global__ __launch_bounds__(256, 2) void vq_stage1_kernel(
    const float* __restrict__ z, const unsigned short* __restrict__ bp,
    const float* __restrict__ enorm, float2* __restrict__ pb,
    unsigned* __restrict__ pbi) {
    __shared__ unsigned short Bds[4][8192];   // 64 KB ring
    __shared__ float en_s[512];

    const int t = threadIdx.x;
    const int w = t >> 6, lane = t & 63;
    const int lr = lane & 15, lg = lane >> 4;
    const int nh = blockIdx.x & 1;
    const long r0 = (long)(blockIdx.x >> 1) * 128 + w * 32;
    const unsigned short* bsrc = bp + (size_t)(nh * 16) * 8192 + lane * 8;

    en_s[t]       = enorm[nh * 512 + t];
    en_s[t + 256] = enorm[nh * 512 + 256 + t];

    bf16x8 ah[2][8];
    #pragma unroll
    for (int m = 0; m < 2; ++m) {
        const float* zr = z + (r0 + m * 16 + lr) * C_DIM + lg * 8;
        #pragma unroll
        for (int kc = 0; kc < 8; ++kc) {
            float4 v0 = *reinterpret_cast<const float4*>(zr + kc * 32);
            float4 v1 = *reinterpret_cast<const float4*>(zr + kc * 32 + 4);
            float vs[8] = {v0.x, v0.y, v0.z, v0.w, v1.x, v1.y, v1.z, v1.w};
            unsigned hp[4];
            #pragma unroll
            for (int p = 0; p < 4; ++p)
                hp[p] = (unsigned)bf16rne(vs[2 * p]) |
                        ((unsigned)bf16rne(vs[2 * p + 1]) << 16);
            ah[m][kc] = __builtin_bit_cast(bf16x8, *reinterpret_cast<uint4*>(hp));
        }
    }
    __syncthreads();   // en_s visible

#define STG1(c) {                                                       \
    unsigned short* db = &Bds[(c) & 3][0];                              \
    const unsigned short* gs = bsrc + (size_t)(c) * 8192;               \
    _Pragma("unroll") for (int rd = 0; rd < 4; ++rd) {                  \
        int s_ = rd * 4 + w;                                            \
        GLOAD_LDS16(gs + s_ * 512, db + s_ * 512); } }

    STG1(0); STG1(1); STG1(2);   // 12 loads/thread in flight

    float b1[2][4], b2[2][4]; unsigned i1[2][4];
    #pragma unroll
    for (int m = 0; m < 2; ++m)
        #pragma unroll
        for (int r = 0; r < 4; ++r) { b1[m][r] = 3.4e38f; b2[m][r] = 3.4e38f; i1[m][r] = 0; }

    #pragma unroll 1
    for (int c = 0; c < 16; ++c) {
        if (c <= 13)      { asm volatile("s_waitcnt vmcnt(8)" ::: "memory"); }
        else if (c == 14) { asm volatile("s_waitcnt vmcnt(4)" ::: "memory"); }
        else              { asm volatile("s_waitcnt vmcnt(0)" ::: "memory"); }
        __builtin_amdgcn_s_barrier();   // chunk c ready everywhere; c-1 readers done
        if (c < 13) STG1(c + 3);        // into slot (c-1)&3, just proven idle

        f32x4 a00 = {0.f,0.f,0.f,0.f}, a01 = {0.f,0.f,0.f,0.f};
        f32x4 a10 = {0.f,0.f,0.f,0.f}, a11 = {0.f,0.f,0.f,0.f};
        const unsigned short* bb = &Bds[c & 3][lane * 8];
        __builtin_amdgcn_s_setprio(1);
        #pragma unroll
        for (int kc = 0; kc < 8; ++kc) {
            bf16x8 bh0 = *reinterpret_cast<const bf16x8*>(bb + kc * 512);
            bf16x8 bh1 = *reinterpret_cast<const bf16x8*>(bb + (8 + kc) * 512);
            a00 = __builtin_amdgcn_mfma_f32_16x16x32_bf16(ah[0][kc], bh0, a00, 0, 0, 0);
            a10 = __builtin_amdgcn_mfma_f32_16x16x32_bf16(ah[1][kc], bh0, a10, 0, 0, 0);
            a01 = __builtin_amdgcn_mfma_f32_16x16x32_bf16(ah[0][kc], bh1, a01, 0, 0, 0);
            a11 = __builtin_amdgcn_mfma_f32_16x16x32_bf16(ah[1][kc], bh1, a11, 0, 0, 0);
        }
        __builtin_amdgcn_s_setprio(0);

        #pragma unroll
        for (int nf = 0; nf < 2; ++nf) {
            const int cl = c * 32 + nf * 16 + lr;
            const float en = en_s[cl];
            const unsigned code = (unsigned)(nh * 512 + cl);
            #pragma unroll
            for (int r = 0; r < 4; ++r) {
                float d0 = fmaf(-2.f, (nf ? a01[r] : a00[r]), en);
                if (d0 < b1[0][r]) { b2[0][r] = b1[0][r]; b1[0][r] = d0; i1[0][r] = code; }
                else if (d0 < b2[0][r]) { b2[0][r] = d0; }
                float d1 = fmaf(-2.f, (nf ? a11[r] : a10[r]), en);
                if (d1 < b1[1][r]) { b2[1][r] = b1[1][r]; b1[1][r] = d1; i1[1][r] = code; }
                else if (d1 < b2[1][r]) { b2[1][r] = d1; }
            }
        }
    }
#undef STG1

    #pragma unroll
    for (int m = 0; m < 2; ++m)
        #pragma unroll
        for (int r = 0; r < 4; ++r) {
            float v1 = b1[m][r], v2 = b2[m][r]; unsigned j1 = i1[m][r];
            #pragma unroll
            for (int off = 8; off; off >>= 1) {
                float    ov1 = __shfl_xor(v1, off, 64);
                float    ov2 = __shfl_xor(v2, off, 64);
                unsigned oj1 = (unsigned)__shfl_xor((int)j1, off, 64);
                if (ov1 < v1 || (ov1 == v1 && oj1 < j1)) {
                    v2 = fminf(v1, ov2); v1 = ov1; j1 = oj1;
                } else {
                    v2 = fminf(v2, ov1);
                }
            }
            if (lr == 0) {
                long row = r0 + m * 16 + lg * 4 + r;
                pb [row * 2 + nh] = make_float2(v1, v2);
                pbi[row * 2 + nh] = j1;
            }
        }
}

// ---------- finalize+gather: merge halves, idx, stage-2 flag, z_q ----------
__global__ __launch_bounds__(256) void finalize_gather_kernel(
    const float* __restrict__ emb, const float2* __restrict__ pb,
    const unsigned* __restrict__ pbi, float* __restrict__ zq,
    float* __restrict__ idx_out, unsigned* __restrict__ meta,
    unsigned* __restrict__ rlist) {
    const long row = (long)blockIdx.x * 4 + (threadIdx.x >> 6);
    const int lane = threadIdx.x & 63;
    float2   p0 = pb [row * 2 + 0], p1 = pb [row * 2 + 1];
    unsigned j0 = pbi[row * 2 + 0], j1 = pbi[row * 2 + 1];
    float B1, B2; unsigned I1;
    if (p1.x < p0.x) { B1 = p1.x; I1 = j1; B2 = fminf(p0.x, p1.y); }
    else             { B1 = p0.x; I1 = j0; B2 = fminf(p0.y, p1.x); }
    if (lane == 0) {
        idx_out[row] = (float)I1;
        if (B2 - B1 <= MARGIN1) rlist[atomicAdd(meta, 1u)] = (unsigned)row;
    }
    float4 v = reinterpret_cast<const float4*>(emb)[(size_t)I1 * 64 + lane];
    reinterpret_cast<float4*>(zq)[row * 64 + lane] = v;   // flagged rows overwritten later
}

// ---------- stage 2: 3-pass re-rank, item = (16-row group) x (256-code quarter) ----------
__global__ __launch_bounds__(256) void vq_stage2_kernel(
    const float* __restrict__ z, const unsigned short* __restrict__ bp,
    const float* __restrict__ enorm, const unsigned* __restrict__ meta,
    const unsigned* __restrict__ rlist, float2* __restrict__ pb2,
    unsigned* __restrict__ pbi2) {
    __shared__ float en_s[NCODE];
    const int t = threadIdx.x, w = t >> 6, lane = t & 63;
    const int lr = lane & 15, lg = lane >> 4;
    en_s[t] = enorm[t]; en_s[t + 256] = enorm[t + 256];
    en_s[t + 512] = enorm[t + 512]; en_s[t + 768] = enorm[t + 768];
    __syncthreads();
    const unsigned cnt = meta[0];
    const unsigned nitems = ((cnt + 15) >> 4) << 2;   // groups * 4 quarters

    for (unsigned item = blockIdx.x * 4 + (unsigned)w; item < nitems;
         item += gridDim.x * 4) {
        const unsigned g = item >> 2, q = item & 3;
        const unsigned base = g * 16;
        unsigned slot = base + (unsigned)lr;
        unsigned row = rlist[slot < cnt ? slot : 0];

        bf16x8 ah[8], al[8];
        const float* zr = z + (size_t)row * C_DIM + lg * 8;
        #pragma unroll
        for (int kc = 0; kc < 8; ++kc) {
            float4 v0 = *reinterpret_cast<const float4*>(zr + kc * 32);
            float4 v1 = *reinterpret_cast<const float4*>(zr + kc * 32 + 4);
            float vs[8] = {v0.x, v0.y, v0.z, v0.w, v1.x, v1.y, v1.z, v1.w};
            unsigned short hv[8], lv[8];
            #pragma unroll
            for (int jj = 0; jj < 8; ++jj) bf16split(vs[jj], hv[jj], lv[jj]);
            unsigned hp[4] = {
                (unsigned)hv[0] | ((unsigned)hv[1] << 16), (unsigned)hv[2] | ((unsigned)hv[3] << 16),
                (unsigned)hv[4] | ((unsigned)hv[5] << 16), (unsigned)hv[6] | ((unsigned)hv[7] << 16)};
            unsigned lp[4] = {
                (unsigned)lv[0] | ((unsigned)lv[1] << 16), (unsigned)lv[2] | ((unsigned)lv[3] << 16),
                (unsigned)lv[4] | ((unsigned)lv[5] << 16), (unsigned)lv[6] | ((unsigned)lv[7] << 16)};
            ah[kc] = __builtin_bit_cast(bf16x8, *reinterpret_cast<uint4*>(hp));
            al[kc] = __builtin_bit_cast(bf16x8, *reinterpret_cast<uint4*>(lp));
        }

        float b1[4], b2[4]; unsigned i1[4];
        #pragma unroll
        for (int r = 0; r < 4; ++r) { b1[r] = 3.4e38f; b2[r] = 3.4e38f; i1[r] = 0; }

        #pragma unroll 1
        for (int cc = 0; cc < 8; ++cc) {
            const int c = (int)q * 8 + cc;
            f32x4 hh0 = {0.f,0.f,0.f,0.f}, hh1 = {0.f,0.f,0.f,0.f};
            f32x4 hl0 = {0.f,0.f,0.f,0.f}, hl1 = {0.f,0.f,0.f,0.f};
            f32x4 lh0 = {0.f,0.f,0.f,0.f}, lh1 = {0.f,0.f,0.f,0.f};
            const unsigned short* cb = bp + (size_t)c * 8192 + lane * 8;
            #pragma unroll
            for (int kc = 0; kc < 8; ++kc) {
                bf16x8 bh0 = *reinterpret_cast<const bf16x8*>(cb + kc * 512);
                bf16x8 bh1 = *reinterpret_cast<const bf16x8*>(cb + (8 + kc) * 512);
                bf16x8 bl0 = *reinterpret_cast<const bf16x8*>(cb + BP_LO_OFF + kc * 512);
                bf16x8 bl1 = *reinterpret_cast<const bf16x8*>(cb + BP_LO_OFF + (8 + kc) * 512);
                hh0 = __builtin_amdgcn_mfma_f32_16x16x32_bf16(ah[kc], bh0, hh0, 0, 0, 0);
                hh1 = __builtin_amdgcn_mfma_f32_16x16x32_bf16(ah[kc], bh1, hh1, 0, 0, 0);
                lh0 = __builtin_amdgcn_mfma_f32_16x16x32_bf16(al[kc], bh0, lh0, 0, 0, 0);
                lh1 = __builtin_amdgcn_mfma_f32_16x16x32_bf16(al[kc], bh1, lh1, 0, 0, 0);
                hl0 = __builtin_amdgcn_mfma_f32_16x16x32_bf16(ah[kc], bl0, hl0, 0, 0, 0);
                hl1 = __builtin_amdgcn_mfma_f32_16x16x32_bf16(ah[kc], bl1, hl1, 0, 0, 0);
            }
            #pragma unroll
            for (int nf = 0; nf < 2; ++nf) {
                const unsigned code = (unsigned)(c * 32 + nf * 16 + lr);
                const float en = en_s[code];
                #pragma unroll
                for (int r = 0; r < 4; ++r) {
                    float s3 = nf ? (hh1[r] + hl1[r] + lh1[r]) : (hh0[r] + hl0[r] + lh0[r]);
                    float d = fmaf(-2.f, s3, en);
                    if (d < b1[r]) { b2[r] = b1[r]; b1[r] = d; i1[r] = code; }
                    else if (d < b2[r]) { b2[r] = d; }
                }
            }
        }

        #pragma unroll
        for (int r = 0; r < 4; ++r) {
            float v1 = b1[r], v2 = b2[r]; unsigned j1 = i1[r];
            #pragma unroll
            for (int off = 8; off; off >>= 1) {
                float    ov1 = __shfl_xor(v1, off, 64);
                float    ov2 = __shfl_xor(v2, off, 64);
                unsigned oj1 = (unsigned)__shfl_xor((int)j1, off, 64);
                if (ov1 < v1 || (ov1 == v1 && oj1 < j1)) {
                    v2 = fminf(v1, ov2); v1 = ov1; j1 = oj1;
                } else {
                    v2 = fminf(v2, ov1);
                }
            }
            if (lr == 0) {
                unsigned sl = base + (unsigned)(lg * 4 + r);
                if (sl < cnt) {
                    pb2 [sl * 4 + q] = make_float2(v1, v2);
                    pbi2[sl * 4 + q] = j1;
                }
            }
        }
    }
}

// ---------- finalize2: merge 4 quarters per flagged row, idx + z_q + rescue flag ----------
__global__ __launch_bounds__(256) void finalize2_kernel(
    const float* __restrict__ emb, const unsigned* __restrict__ meta,
    const unsigned* __restrict__ rlist, const float2* __restrict__ pb2,
    const unsigned* __restrict__ pbi2, float* __restrict__ zq,
    float* __restrict__ idx_out, unsigned* __restrict__ meta2,
    unsigned* __restrict__ rlist2) {
    const int w = threadIdx.x >> 6, lane = threadIdx.x & 63;
    const unsigned cnt = meta[0];
    for (unsigned slot = blockIdx.x * 4 + (unsigned)w; slot < cnt;
         slot += gridDim.x * 4) {
        unsigned row = rlist[slot];
        float B1 = 3.4e38f, B2 = 3.4e38f; unsigned I1 = 0;
        #pragma unroll
        for (int s = 0; s < 4; ++s) {   // ascending quarter = ascending codes
            float2   p = pb2 [slot * 4 + s];
            unsigned j = pbi2[slot * 4 + s];
            if (p.x < B1) { B2 = fminf(B1, p.y); B1 = p.x; I1 = j; }
            else          { B2 = fminf(B2, p.x); }
        }
        if (lane == 0) {
            idx_out[row] = (float)I1;
            if (B2 - B1 <= MARGIN2) rlist2[atomicAdd(meta2, 1u)] = row;
        }
        float4 v = reinterpret_cast<const float4*>(emb)[(size_t)I1 * 64 + lane];
        reinterpret_cast<float4*>(zq)[(size_t)row * 64 + lane] = v;
    }
}

// ---------- rescue: exact fp32 argmin for stage-2 flagged rows ----------
__global__ __launch_bounds__(256) void rescue_kernel(
    const float* __restrict__ z, const float* __restrict__ emb,
    const float* __restrict__ enorm, const unsigned* __restrict__ meta2,
    const unsigned* __restrict__ rlist2, float* __restrict__ zq,
    float* __restrict__ idx_out) {
    __shared__ float zrow[C_DIM];
    __shared__ float rd[256];
    __shared__ unsigned rix[256];
    const unsigned cnt = meta2[0];
    for (unsigned li = blockIdx.x; li < cnt; li += gridDim.x) {
        unsigned row = rlist2[li];
        __syncthreads();
        if (threadIdx.x < 64) {
            float4 v = reinterpret_cast<const float4*>(z)[(size_t)row * 64 + threadIdx.x];
            reinterpret_cast<float4*>(zrow)[threadIdx.x] = v;
        }
        __syncthreads();
        const int c = threadIdx.x;
        float a0 = 0.f, a1 = 0.f, a2 = 0.f, a3 = 0.f;
        const float4* zp = reinterpret_cast<const float4*>(zrow);
        const float4* e0 = reinterpret_cast<const float4*>(emb + (size_t)(c)       * C_DIM);
        const float4* e1 = reinterpret_cast<const float4*>(emb + (size_t)(c + 256) * C_DIM);
        const float4* e2 = reinterpret_cast<const float4*>(emb + (size_t)(c + 512) * C_DIM);
        const float4* e3 = reinterpret_cast<const float4*>(emb + (size_t)(c + 768) * C_DIM);
        #pragma unroll 8
        for (int k = 0; k < 64; ++k) {
            float4 z4 = zp[k];
            float4 f0 = e0[k], f1 = e1[k], f2 = e2[k], f3 = e3[k];
            a0 = fmaf(z4.x, f0.x, a0); a0 = fmaf(z4.y, f0.y, a0);
            a0 = fmaf(z4.z, f0.z, a0); a0 = fmaf(z4.w, f0.w, a0);
            a1 = fmaf(z4.x, f1.x, a1); a1 = fmaf(z4.y, f1.y, a1);
            a1 = fmaf(z4.z, f1.z, a1); a1 = fmaf(z4.w, f1.w, a1);
            a2 = fmaf(z4.x, f2.x, a2); a2 = fmaf(z4.y, f2.y, a2);
            a2 = fmaf(z4.z, f2.z, a2); a2 = fmaf(z4.w, f2.w, a2);
            a3 = fmaf(z4.x, f3.x, a3); a3 = fmaf(z4.y, f3.y, a3);
            a3 = fmaf(z4.z, f3.z, a3); a3 = fmaf(z4.w, f3.w, a3);
        }
        float d0 = fmaf(-2.f, a0, enorm[c]);
        float d1 = fmaf(-2.f, a1, enorm[c + 256]);
        float d2 = fmaf(-2.f, a2, enorm[c + 512]);
        float d3 = fmaf(-2.f, a3, enorm[c + 768]);
        float bd = d0; unsigned bi = (unsigned)c;
        if (d1 < bd) { bd = d1; bi = (unsigned)(c + 256); }
        if (d2 < bd) { bd = d2; bi = (unsigned)(c + 512); }
        if (d3 < bd) { bd = d3; bi = (unsigned)(c + 768); }
        rd[threadIdx.x] = bd; rix[threadIdx.x] = bi;
        __syncthreads();
        for (int s = 128; s; s >>= 1) {
            if (threadIdx.x < (unsigned)s) {
                float od = rd[threadIdx.x + s]; unsigned oi = rix[threadIdx.x + s];
                if (od < rd[threadIdx.x] ||
                    (od == rd[threadIdx.x] && oi < rix[threadIdx.x])) {
                    rd[threadIdx.x] = od; rix[threadIdx.x] = oi;
                }
            }
            __syncthreads();
        }
        unsigned code = rix[0];
        if (threadIdx.x < 64) {
            float4 v = reinterpret_cast<const float4*>(emb)[(size_t)code * 64 + threadIdx.x];
            reinterpret_cast<float4*>(zq)[(size_t)row * 64 + threadIdx.x] = v;
        }
        if (threadIdx.x == 0) idx_out[row] = (float)code;
    }
}

extern "C" void kernel_launch(void* const* d_in, const int* in_sizes, int n_in,
                              void* d_out, int out_size, void* d_ws, size_t ws_size,
                              hipStream_t stream) {
    const float* z   = (const float*)d_in[0];
    const float* emb = (const float*)d_in[1];
    const int n = in_sizes[0] / C_DIM;   // 32768

    float* zq      = (float*)d_out;
    float* idx_out = zq + (size_t)n * C_DIM;

    char* ws = (char*)d_ws;
    float*          enorm  = (float*)(ws + WS_ENORM);
    unsigned*       meta   = (unsigned*)(ws + WS_META);
    unsigned*       rlist  = (unsigned*)(ws + WS_RLIST);
    unsigned*       rlist2 = (unsigned*)(ws + WS_RLIST2);
    unsigned short* bp     = (unsigned short*)(ws + WS_BP);
    float2*         pb     = (float2*)(ws + WS_PB);
    unsigned*       pbi    = (unsigned*)(ws + WS_PBI);
    float2*         pb2    = (float2*)(ws + WS_PB2);
    unsigned*       pbi2   = (unsigned*)(ws + WS_PBI2);

    prep_kernel<<<128, 256, 0, stream>>>(emb, bp, enorm, meta);
    vq_stage1_kernel<<<(n / 128) * 2, 256, 0, stream>>>(z, bp, enorm, pb, pbi);
    finalize_gather_kernel<<<n / 4, 256, 0, stream>>>(emb, pb, pbi, zq, idx_out,
                                                      meta, rlist);
    vq_stage2_kernel<<<512, 256, 0, stream>>>(z, bp, enorm, meta, rlist, pb2, pbi2);
    finalize2_kernel<<<512, 256, 0, stream>>>(emb, meta, rlist, pb2, pbi2,
                                              zq, idx_out, meta + 1, rlist2);
    rescue_kernel<<<256, 256, 0, stream>>>(z, emb, enorm, meta + 1, rlist2,
                                           zq, idx_out);
}

// Round 14
// 133.748 us; speedup vs baseline: 1.6392x; 1.0026x over previous
//
#include <hip/hip_runtime.h>

#define C_DIM 256
#define NCODE 1024
#define MARGIN1 0.35f   // stage-1 screen (1-pass err-diff sigma ~0.07 -> 5 sigma)
#define MARGIN2 0.02f   // stage-2 screen (3-pass, validated R5+)

typedef __bf16 bf16x8 __attribute__((ext_vector_type(8)));
typedef float f32x4 __attribute__((ext_vector_type(4)));

// ws layout (byte offsets)
#define WS_ENORM  0        // f32[1024]
#define WS_META   4096     // u32[2]: stage1 count, stage2 count
#define WS_RLIST  8192     // u32[32768]
#define WS_RLIST2 139264   // u32[32768]
#define WS_BP     270336   // bf16 frag-order: hi[32 chunks][8192 u16], lo same (+512KB)
#define WS_PB     1318912  // float2[32768][2]  (stage-1 half partials)
#define WS_PBI    1843200  // u32[32768][2]

#define BP_LO_OFF 262144   // u16 offset of lo region within bp

#define GLOAD_LDS16(g, s)                                                            \
  __builtin_amdgcn_global_load_lds(                                                  \
      (const __attribute__((address_space(1))) unsigned int*)(g),                    \
      (__attribute__((address_space(3))) unsigned int*)(s), 16, 0, 0)

__device__ __forceinline__ unsigned short bf16rne(float x) {
    unsigned u = __float_as_uint(x);
    return (unsigned short)((u + 0x7FFFu + ((u >> 16) & 1u)) >> 16);
}
__device__ __forceinline__ void bf16split(float x, unsigned short& h, unsigned short& l) {
    unsigned u  = __float_as_uint(x);
    unsigned rh = (u + 0x7FFFu + ((u >> 16) & 1u)) & 0xFFFF0000u;   // RNE to bf16
    float    lf = x - __uint_as_float(rh);                          // exact
    h = (unsigned short)(rh >> 16);
    l = bf16rne(lf);
}

// ---------- prep: emb -> frag-order B' (hi|lo) + enorm + meta reset (fused) ----------
__global__ __launch_bounds__(256) void prep_kernel(const float* __restrict__ emb,
                                                   unsigned short* __restrict__ bp,
                                                   float* __restrict__ enorm,
                                                   unsigned* __restrict__ meta) {
    int tid = blockIdx.x * 256 + threadIdx.x;   // 32768 = 1024 codes x 32
    if (tid < 2) meta[tid] = 0u;
    int j   = tid >> 5;                         // code
    int u   = tid & 31;
    int kc  = u >> 2, lg = u & 3;
    const float* src = emb + (size_t)j * C_DIM + kc * 32 + lg * 8;
    float4 v0 = *reinterpret_cast<const float4*>(src);
    float4 v1 = *reinterpret_cast<const float4*>(src + 4);
    float vs[8] = {v0.x, v0.y, v0.z, v0.w, v1.x, v1.y, v1.z, v1.w};
    unsigned short h[8], l[8];
    float s = 0.f;
    #pragma unroll
    for (int k = 0; k < 8; ++k) {
        bf16split(vs[k], h[k], l[k]);
        s = fmaf(vs[k], vs[k], s);
    }
    #pragma unroll
    for (int off = 1; off < 32; off <<= 1) s += __shfl_xor(s, off, 64);
    if (u == 0) enorm[j] = s;

    int chunk = j >> 5, nf = (j >> 4) & 1, lr = j & 15;
    int lane  = lg * 16 + lr;
    size_t base = (size_t)chunk * 8192 + (size_t)(nf * 8 + kc) * 512 + lane * 8;
    uint4 hp, lp;
    hp.x = (unsigned)h[0] | ((unsigned)h[1] << 16);
    hp.y = (unsigned)h[2] | ((unsigned)h[3] << 16);
    hp.z = (unsigned)h[4] | ((unsigned)h[5] << 16);
    hp.w = (unsigned)h[6] | ((unsigned)h[7] << 16);
    lp.x = (unsigned)l[0] | ((unsigned)l[1] << 16);
    lp.y = (unsigned)l[2] | ((unsigned)l[3] << 16);
    lp.z = (unsigned)l[4] | ((unsigned)l[5] << 16);
    lp.w = (unsigned)l[6] | ((unsigned)l[7] << 16);
    *reinterpret_cast<uint4*>(bp + base)             = hp;
    *reinterpret_cast<uint4*>(bp + BP_LO_OFF + base) = lp;
}

// ---------- stage 1: 1-pass hi-only MFMA screen, 3-deep ring, 3 blocks/CU ----------
// iter c: vmcnt(4) {chunk c landed; c+1 in flight} -> s_barrier {chunk c visible
// everywhere AND all waves done with chunk c-1} -> stage chunk c+2 into slot
// (c-1)%3 (just proven idle) -> compute chunk c from slot c%3.
__global__ __launch_bounds__(256, 3) void vq_stage1_kernel(
    const float* __restrict__ z, const unsigned short* __restrict__ bp,
    const float* __restrict__ enorm, float2* __restrict__ pb,
    unsigned* __restrict__ pbi) {
    __shared__ unsigned short Bds[3][8192];   // 48 KB ring
    __shared__ float en_s[512];

    const int t = threadIdx.x;
    const int w = t >> 6, lane = t & 63;
    const int lr = lane & 15, lg = lane >> 4;
    const int nh = blockIdx.x & 1;
    const long r0 = (long)(blockIdx.x >> 1) * 128 + w * 32;
    const unsigned short* bsrc = bp + (size_t)(nh * 16) * 8192 + lane * 8;

    en_s[t]       = enorm[nh * 512 + t];
    en_s[t + 256] = enorm[nh * 512 + 256 + t];

    bf16x8 ah[2][8];
    #pragma unroll
    for (int m = 0; m < 2; ++m) {
        const float* zr = z + (r0 + m * 16 + lr) * C_DIM + lg * 8;
        #pragma unroll
        for (int kc = 0; kc < 8; ++kc) {
            float4 v0 = *reinterpret_cast<const float4*>(zr + kc * 32);
            float4 v1 = *reinterpret_cast<const float4*>(zr + kc * 32 + 4);
            float vs[8] = {v0.x, v0.y, v0.z, v0.w, v1.x, v1.y, v1.z, v1.w};
            unsigned hp[4];
            #pragma unroll
            for (int p = 0; p < 4; ++p)
                hp[p] = (unsigned)bf16rne(vs[2 * p]) |
                        ((unsigned)bf16rne(vs[2 * p + 1]) << 16);
            ah[m][kc] = __builtin_bit_cast(bf16x8, *reinterpret_cast<uint4*>(hp));
        }
    }
    __syncthreads();   // en_s visible

#define STG1(c, sl) {                                                   \
    unsigned short* db = &Bds[sl][0];                                   \
    const unsigned short* gs = bsrc + (size_t)(c) * 8192;               \
    _Pragma("unroll") for (int rd = 0; rd < 4; ++rd) {                  \
        int s_ = rd * 4 + w;                                            \
        GLOAD_LDS16(gs + s_ * 512, db + s_ * 512); } }

    STG1(0, 0); STG1(1, 1);   // 8 loads/thread in flight

    float b1[2][4], b2[2][4]; unsigned i1[2][4];
    #pragma unroll
    for (int m = 0; m < 2; ++m)
        #pragma unroll
        for (int r = 0; r < 4; ++r) { b1[m][r] = 3.4e38f; b2[m][r] = 3.4e38f; i1[m][r] = 0; }

    int rs = 0, ws = 2;   // read slot (c%3), write slot ((c+2)%3)
    #pragma unroll 1
    for (int c = 0; c < 16; ++c) {
        if (c <= 14) { asm volatile("s_waitcnt vmcnt(4)" ::: "memory"); }
        else         { asm volatile("s_waitcnt vmcnt(0)" ::: "memory"); }
        __builtin_amdgcn_s_barrier();   // chunk c ready everywhere; c-1 readers done
        if (c < 14) STG1(c + 2, ws);    // into slot (c-1)%3, just proven idle

        f32x4 a00 = {0.f,0.f,0.f,0.f}, a01 = {0.f,0.f,0.f,0.f};
        f32x4 a10 = {0.f,0.f,0.f,0.f}, a11 = {0.f,0.f,0.f,0.f};
        const unsigned short* bb = &Bds[rs][lane * 8];
        __builtin_amdgcn_s_setprio(1);
        #pragma unroll
        for (int kc = 0; kc < 8; ++kc) {
            bf16x8 bh0 = *reinterpret_cast<const bf16x8*>(bb + kc * 512);
            bf16x8 bh1 = *reinterpret_cast<const bf16x8*>(bb + (8 + kc) * 512);
            a00 = __builtin_amdgcn_mfma_f32_16x16x32_bf16(ah[0][kc], bh0, a00, 0, 0, 0);
            a10 = __builtin_amdgcn_mfma_f32_16x16x32_bf16(ah[1][kc], bh0, a10, 0, 0, 0);
            a01 = __builtin_amdgcn_mfma_f32_16x16x32_bf16(ah[0][kc], bh1, a01, 0, 0, 0);
            a11 = __builtin_amdgcn_mfma_f32_16x16x32_bf16(ah[1][kc], bh1, a11, 0, 0, 0);
        }
        __builtin_amdgcn_s_setprio(0);

        #pragma unroll
        for (int nf = 0; nf < 2; ++nf) {
            const int cl = c * 32 + nf * 16 + lr;
            const float en = en_s[cl];
            const unsigned code = (unsigned)(nh * 512 + cl);
            #pragma unroll
            for (int r = 0; r < 4; ++r) {
                float d0 = fmaf(-2.f, (nf ? a01[r] : a00[r]), en);
                if (d0 < b1[0][r]) { b2[0][r] = b1[0][r]; b1[0][r] = d0; i1[0][r] = code; }
                else if (d0 < b2[0][r]) { b2[0][r] = d0; }
                float d1 = fmaf(-2.f, (nf ? a11[r] : a10[r]), en);
                if (d1 < b1[1][r]) { b2[1][r] = b1[1][r]; b1[1][r] = d1; i1[1][r] = code; }
                else if (d1 < b2[1][r]) { b2[1][r] = d1; }
            }
        }
        rs = rs + 1; if (rs == 3) rs = 0;
        ws = ws + 1; if (ws == 3) ws = 0;
    }
#undef STG1

    #pragma unroll
    for (int m = 0; m < 2; ++m)
        #pragma unroll
        for (int r = 0; r < 4; ++r) {
            float v1 = b1[m][r], v2 = b2[m][r]; unsigned j1 = i1[m][r];
            #pragma unroll
            for (int off = 8; off; off >>= 1) {
                float    ov1 = __shfl_xor(v1, off, 64);
                float    ov2 = __shfl_xor(v2, off, 64);
                unsigned oj1 = (unsigned)__shfl_xor((int)j1, off, 64);
                if (ov1 < v1 || (ov1 == v1 && oj1 < j1)) {
                    v2 = fminf(v1, ov2); v1 = ov1; j1 = oj1;
                } else {
                    v2 = fminf(v2, ov1);
                }
            }
            if (lr == 0) {
                long row = r0 + m * 16 + lg * 4 + r;
                pb [row * 2 + nh] = make_float2(v1, v2);
                pbi[row * 2 + nh] = j1;
            }
        }
}

// ---------- finalize+gather: merge halves, idx, stage-2 flag, z_q ----------
__global__ __launch_bounds__(256) void finalize_gather_kernel(
    const float* __restrict__ emb, const float2* __restrict__ pb,
    const unsigned* __restrict__ pbi, float* __restrict__ zq,
    float* __restrict__ idx_out, unsigned* __restrict__ meta,
    unsigned* __restrict__ rlist, int n4) {
    const int lane = threadIdx.x & 63;
    for (long r4 = blockIdx.x; r4 < n4; r4 += gridDim.x) {
        const long row = r4 * 4 + (threadIdx.x >> 6);
        float2   p0 = pb [row * 2 + 0], p1 = pb [row * 2 + 1];
        unsigned j0 = pbi[row * 2 + 0], j1 = pbi[row * 2 + 1];
        float B1, B2; unsigned I1;
        if (p1.x < p0.x) { B1 = p1.x; I1 = j1; B2 = fminf(p0.x, p1.y); }
        else             { B1 = p0.x; I1 = j0; B2 = fminf(p0.y, p1.x); }
        if (lane == 0) {
            idx_out[row] = (float)I1;
            if (B2 - B1 <= MARGIN1) rlist[atomicAdd(meta, 1u)] = (unsigned)row;
        }
        float4 v = reinterpret_cast<const float4*>(emb)[(size_t)I1 * 64 + lane];
        reinterpret_cast<float4*>(zq)[row * 64 + lane] = v;   // flagged rows overwritten later
    }
}

// ---------- stage 2 (fused finalize2): block = 16-row group; wave q = quarter q ----------
// 3-pass re-rank of flagged rows; in-block quarter merge -> idx + z_q + rescue flag.
__global__ __launch_bounds__(256) void vq_stage2_kernel(
    const float* __restrict__ z, const unsigned short* __restrict__ bp,
    const float* __restrict__ enorm, const float* __restrict__ emb,
    const unsigned* __restrict__ meta, const unsigned* __restrict__ rlist,
    float* __restrict__ zq, float* __restrict__ idx_out,
    unsigned* __restrict__ meta2, unsigned* __restrict__ rlist2) {
    __shared__ float en_s[NCODE];
    __shared__ float m1s[16][4], m2s[16][4];
    __shared__ unsigned mis[16][4];
    __shared__ unsigned codes_s[16];
    const int t = threadIdx.x, q = t >> 6, lane = t & 63;
    const int lr = lane & 15, lg = lane >> 4;
    en_s[t] = enorm[t]; en_s[t + 256] = enorm[t + 256];
    en_s[t + 512] = enorm[t + 512]; en_s[t + 768] = enorm[t + 768];
    __syncthreads();
    const unsigned cnt = meta[0];
    const unsigned ngroups = (cnt + 15) >> 4;

    for (unsigned g = blockIdx.x; g < ngroups; g += gridDim.x) {
        const unsigned base = g * 16;
        unsigned slot = base + (unsigned)lr;
        unsigned row = rlist[slot < cnt ? slot : 0];

        // A: this row's z, split hi/lo (redundant across waves; negligible)
        bf16x8 ah[8], al[8];
        const float* zr = z + (size_t)row * C_DIM + lg * 8;
        #pragma unroll
        for (int kc = 0; kc < 8; ++kc) {
            float4 v0 = *reinterpret_cast<const float4*>(zr + kc * 32);
            float4 v1 = *reinterpret_cast<const float4*>(zr + kc * 32 + 4);
            float vs[8] = {v0.x, v0.y, v0.z, v0.w, v1.x, v1.y, v1.z, v1.w};
            unsigned short hv[8], lv[8];
            #pragma unroll
            for (int jj = 0; jj < 8; ++jj) bf16split(vs[jj], hv[jj], lv[jj]);
            unsigned hp[4] = {
                (unsigned)hv[0] | ((unsigned)hv[1] << 16), (unsigned)hv[2] | ((unsigned)hv[3] << 16),
                (unsigned)hv[4] | ((unsigned)hv[5] << 16), (unsigned)hv[6] | ((unsigned)hv[7] << 16)};
            unsigned lp[4] = {
                (unsigned)lv[0] | ((unsigned)lv[1] << 16), (unsigned)lv[2] | ((unsigned)lv[3] << 16),
                (unsigned)lv[4] | ((unsigned)lv[5] << 16), (unsigned)lv[6] | ((unsigned)lv[7] << 16)};
            ah[kc] = __builtin_bit_cast(bf16x8, *reinterpret_cast<uint4*>(hp));
            al[kc] = __builtin_bit_cast(bf16x8, *reinterpret_cast<uint4*>(lp));
        }

        float b1[4], b2[4]; unsigned i1[4];
        #pragma unroll
        for (int r = 0; r < 4; ++r) { b1[r] = 3.4e38f; b2[r] = 3.4e38f; i1[r] = 0; }

        #pragma unroll 1
        for (int cc = 0; cc < 8; ++cc) {
            const int c = q * 8 + cc;
            f32x4 hh0 = {0.f,0.f,0.f,0.f}, hh1 = {0.f,0.f,0.f,0.f};
            f32x4 hl0 = {0.f,0.f,0.f,0.f}, hl1 = {0.f,0.f,0.f,0.f};
            f32x4 lh0 = {0.f,0.f,0.f,0.f}, lh1 = {0.f,0.f,0.f,0.f};
            const unsigned short* cb = bp + (size_t)c * 8192 + lane * 8;
            #pragma unroll
            for (int kc = 0; kc < 8; ++kc) {
                bf16x8 bh0 = *reinterpret_cast<const bf16x8*>(cb + kc * 512);
                bf16x8 bh1 = *reinterpret_cast<const bf16x8*>(cb + (8 + kc) * 512);
                bf16x8 bl0 = *reinterpret_cast<const bf16x8*>(cb + BP_LO_OFF + kc * 512);
                bf16x8 bl1 = *reinterpret_cast<const bf16x8*>(cb + BP_LO_OFF + (8 + kc) * 512);
                hh0 = __builtin_amdgcn_mfma_f32_16x16x32_bf16(ah[kc], bh0, hh0, 0, 0, 0);
                hh1 = __builtin_amdgcn_mfma_f32_16x16x32_bf16(ah[kc], bh1, hh1, 0, 0, 0);
                lh0 = __builtin_amdgcn_mfma_f32_16x16x32_bf16(al[kc], bh0, lh0, 0, 0, 0);
                lh1 = __builtin_amdgcn_mfma_f32_16x16x32_bf16(al[kc], bh1, lh1, 0, 0, 0);
                hl0 = __builtin_amdgcn_mfma_f32_16x16x32_bf16(ah[kc], bl0, hl0, 0, 0, 0);
                hl1 = __builtin_amdgcn_mfma_f32_16x16x32_bf16(ah[kc], bl1, hl1, 0, 0, 0);
            }
            #pragma unroll
            for (int nf = 0; nf < 2; ++nf) {
                const unsigned code = (unsigned)(c * 32 + nf * 16 + lr);
                const float en = en_s[code];
                #pragma unroll
                for (int r = 0; r < 4; ++r) {
                    float s3 = nf ? (hh1[r] + hl1[r] + lh1[r]) : (hh0[r] + hl0[r] + lh0[r]);
                    float d = fmaf(-2.f, s3, en);
                    if (d < b1[r]) { b2[r] = b1[r]; b1[r] = d; i1[r] = code; }
                    else if (d < b2[r]) { b2[r] = d; }
                }
            }
        }

        // cross-lane merge over lr; write quarter partials to LDS
        #pragma unroll
        for (int r = 0; r < 4; ++r) {
            float v1 = b1[r], v2 = b2[r]; unsigned j1 = i1[r];
            #pragma unroll
            for (int off = 8; off; off >>= 1) {
                float    ov1 = __shfl_xor(v1, off, 64);
                float    ov2 = __shfl_xor(v2, off, 64);
                unsigned oj1 = (unsigned)__shfl_xor((int)j1, off, 64);
                if (ov1 < v1 || (ov1 == v1 && oj1 < j1)) {
                    v2 = fminf(v1, ov2); v1 = ov1; j1 = oj1;
                } else {
                    v2 = fminf(v2, ov1);
                }
            }
            if (lr == 0) {
                int rg = lg * 4 + r;
                m1s[rg][q] = v1; m2s[rg][q] = v2; mis[rg][q] = j1;
            }
        }
        __syncthreads();
        if (t < 16) {
            float B1 = 3.4e38f, B2 = 3.4e38f; unsigned I1 = 0;
            #pragma unroll
            for (int s = 0; s < 4; ++s) {   // ascending quarter = ascending codes
                float v1 = m1s[t][s], v2 = m2s[t][s]; unsigned j = mis[t][s];
                if (v1 < B1) { B2 = fminf(B1, v2); B1 = v1; I1 = j; }
                else         { B2 = fminf(B2, v1); }
            }
            unsigned sl = base + (unsigned)t;
            codes_s[t] = I1;
            if (sl < cnt) {
                unsigned rrow = rlist[sl];
                idx_out[rrow] = (float)I1;
                if (B2 - B1 <= MARGIN2) rlist2[atomicAdd(meta2, 1u)] = rrow;
            }
        }
        __syncthreads();
        {   // gather z_q: 16 threads/row, 4 float4 each
            int rr = t >> 4, seg = t & 15;
            unsigned sl = base + (unsigned)rr;
            if (sl < cnt) {
                unsigned rrow = rlist[sl];
                unsigned code = codes_s[rr];
                const float4* ep = reinterpret_cast<const float4*>(emb) + (size_t)code * 64 + seg * 4;
                float4*       op = reinterpret_cast<float4*>(zq) + (size_t)rrow * 64 + seg * 4;
                op[0] = ep[0]; op[1] = ep[1]; op[2] = ep[2]; op[3] = ep[3];
            }
        }
        __syncthreads();   // protect m1s/codes_s before next group iteration
    }
}

// ---------- rescue: exact fp32 argmin for stage-2 flagged rows ----------
__global__ __launch_bounds__(256) void rescue_kernel(
    const float* __restrict__ z, const float* __restrict__ emb,
    const float* __restrict__ enorm, const unsigned* __restrict__ meta2,
    const unsigned* __restrict__ rlist2, float* __restrict__ zq,
    float* __restrict__ idx_out) {
    __shared__ float zrow[C_DIM];
    __shared__ float rd[256];
    __shared__ unsigned rix[256];
    const unsigned cnt = meta2[0];
    for (unsigned li = blockIdx.x; li < cnt; li += gridDim.x) {
        unsigned row = rlist2[li];
        __syncthreads();
        if (threadIdx.x < 64) {
            float4 v = reinterpret_cast<const float4*>(z)[(size_t)row * 64 + threadIdx.x];
            reinterpret_cast<float4*>(zrow)[threadIdx.x] = v;
        }
        __syncthreads();
        const int c = threadIdx.x;
        float a0 = 0.f, a1 = 0.f, a2 = 0.f, a3 = 0.f;
        const float4* zp = reinterpret_cast<const float4*>(zrow);
        const float4* e0 = reinterpret_cast<const float4*>(emb + (size_t)(c)       * C_DIM);
        const float4* e1 = reinterpret_cast<const float4*>(emb + (size_t)(c + 256) * C_DIM);
        const float4* e2 = reinterpret_cast<const float4*>(emb + (size_t)(c + 512) * C_DIM);
        const float4* e3 = reinterpret_cast<const float4*>(emb + (size_t)(c + 768) * C_DIM);
        #pragma unroll 8
        for (int k = 0; k < 64; ++k) {
            float4 z4 = zp[k];
            float4 f0 = e0[k], f1 = e1[k], f2 = e2[k], f3 = e3[k];
            a0 = fmaf(z4.x, f0.x, a0); a0 = fmaf(z4.y, f0.y, a0);
            a0 = fmaf(z4.z, f0.z, a0); a0 = fmaf(z4.w, f0.w, a0);
            a1 = fmaf(z4.x, f1.x, a1); a1 = fmaf(z4.y, f1.y, a1);
            a1 = fmaf(z4.z, f1.z, a1); a1 = fmaf(z4.w, f1.w, a1);
            a2 = fmaf(z4.x, f2.x, a2); a2 = fmaf(z4.y, f2.y, a2);
            a2 = fmaf(z4.z, f2.z, a2); a2 = fmaf(z4.w, f2.w, a2);
            a3 = fmaf(z4.x, f3.x, a3); a3 = fmaf(z4.y, f3.y, a3);
            a3 = fmaf(z4.z, f3.z, a3); a3 = fmaf(z4.w, f3.w, a3);
        }
        float d0 = fmaf(-2.f, a0, enorm[c]);
        float d1 = fmaf(-2.f, a1, enorm[c + 256]);
        float d2 = fmaf(-2.f, a2, enorm[c + 512]);
        float d3 = fmaf(-2.f, a3, enorm[c + 768]);
        float bd = d0; unsigned bi = (unsigned)c;
        if (d1 < bd) { bd = d1; bi = (unsigned)(c + 256); }
        if (d2 < bd) { bd = d2; bi = (unsigned)(c + 512); }
        if (d3 < bd) { bd = d3; bi = (unsigned)(c + 768); }
        rd[threadIdx.x] = bd; rix[threadIdx.x] = bi;
        __syncthreads();
        for (int s = 128; s; s >>= 1) {
            if (threadIdx.x < (unsigned)s) {
                float od = rd[threadIdx.x + s]; unsigned oi = rix[threadIdx.x + s];
                if (od < rd[threadIdx.x] ||
                    (od == rd[threadIdx.x] && oi < rix[threadIdx.x])) {
                    rd[threadIdx.x] = od; rix[threadIdx.x] = oi;
                }
            }
            __syncthreads();
        }
        unsigned code = rix[0];
        if (threadIdx.x < 64) {
            float4 v = reinterpret_cast<const float4*>(emb)[(size_t)code * 64 + threadIdx.x];
            reinterpret_cast<float4*>(zq)[(size_t)row * 64 + threadIdx.x] = v;
        }
        if (threadIdx.x == 0) idx_out[row] = (float)code;
    }
}

extern "C" void kernel_launch(void* const* d_in, const int* in_sizes, int n_in,
                              void* d_out, int out_size, void* d_ws, size_t ws_size,
                              hipStream_t stream) {
    const float* z   = (const float*)d_in[0];
    const float* emb = (const float*)d_in[1];
    const int n = in_sizes[0] / C_DIM;   // 32768

    float* zq      = (float*)d_out;
    float* idx_out = zq + (size_t)n * C_DIM;

    char* ws = (char*)d_ws;
    float*          enorm  = (float*)(ws + WS_ENORM);
    unsigned*       meta   = (unsigned*)(ws + WS_META);
    unsigned*       rlist  = (unsigned*)(ws + WS_RLIST);
    unsigned*       rlist2 = (unsigned*)(ws + WS_RLIST2);
    unsigned short* bp     = (unsigned short*)(ws + WS_BP);
    float2*         pb     = (float2*)(ws + WS_PB);
    unsigned*       pbi    = (unsigned*)(ws + WS_PBI);

    prep_kernel<<<128, 256, 0, stream>>>(emb, bp, enorm, meta);
    vq_stage1_kernel<<<(n / 128) * 2, 256, 0, stream>>>(z, bp, enorm, pb, pbi);
    finalize_gather_kernel<<<2048, 256, 0, stream>>>(emb, pb, pbi, zq, idx_out,
                                                     meta, rlist, n / 4);
    vq_stage2_kernel<<<256, 256, 0, stream>>>(z, bp, enorm, emb, meta, rlist,
                                              zq, idx_out, meta + 1, rlist2);
    rescue_kernel<<<256, 256, 0, stream>>>(z, emb, enorm, meta + 1, rlist2,
                                           zq, idx_out);
}